// Round 12
// baseline (688.840 us; speedup 1.0000x reference)
//
#include <hip/hip_runtime.h>
#include <cstdint>
#include <cstddef>

#define NN 50000
#define EE 800000
#define FIN 32
#define EDD 10
#define GG 512
#define CC 64
#define SCAN_BLK 196        // ceil(NN/256)
#define PRE_BLKS ((EE + 255) / 256)   // 3125
#define G1_BLKS ((NN + 31) / 32)      // 1563
static constexpr float EPSV = 1e-5f;

typedef _Float16 h4 __attribute__((ext_vector_type(4)));
typedef _Float16 h2v __attribute__((ext_vector_type(2)));

union U32H2 { unsigned int u; h2v h; };

__device__ __forceinline__ unsigned int pack2(float a, float b) {
  U32H2 x;
  x.h.x = (_Float16)a;
  x.h.y = (_Float16)b;
  return x.u;
}
__device__ __forceinline__ float2 unpack2(unsigned int u) {
  U32H2 x;
  x.u = u;
  return make_float2((float)x.h.x, (float)x.h.y);
}

__device__ __forceinline__ float lrelu(float x, float s) { return x > 0.f ? x : s * x; }

// ---------------- preprocessing ----------------
// blocks [0, PRE_BLKS): degree count + per-graph node count (atomics, latency-bound)
// blocks [PRE_BLKS, PRE_BLKS+3): per-layer was/wad/weae prep (tiny GEMV, hidden under pre)
__global__ __launch_bounds__(256) void k_pre_prep(
    const int* __restrict__ dst, const int* __restrict__ batch,
    int* __restrict__ deg, float* __restrict__ gcnt,
    const float* __restrict__ w1, const float* __restrict__ s1, const float* __restrict__ d1,
    const float* __restrict__ e1, const float* __restrict__ a1,
    const float* __restrict__ w2, const float* __restrict__ s2, const float* __restrict__ d2,
    const float* __restrict__ e2, const float* __restrict__ a2,
    const float* __restrict__ w3, const float* __restrict__ s3, const float* __restrict__ d3,
    const float* __restrict__ e3, const float* __restrict__ a3,
    float* __restrict__ was1, float* __restrict__ wad1, float* __restrict__ weae1,
    float* __restrict__ was2, float* __restrict__ wad2, float* __restrict__ weae2,
    float* __restrict__ was3, float* __restrict__ wad3, float* __restrict__ weae3) {
  int b = blockIdx.x;
  if (b < PRE_BLKS) {
    int e = b * 256 + threadIdx.x;
    if (e < EE) atomicAdd(&deg[dst[e]], 1);
    if (e < NN) atomicAdd(&gcnt[batch[e]], 1.f);
    return;
  }
  int l = b - PRE_BLKS;
  const float *W, *as_, *ad_, *We, *ae_;
  float *was, *wad, *weae;
  int K, H;
  if (l == 0) { W = w1; as_ = s1; ad_ = d1; We = e1; ae_ = a1; was = was1; wad = wad1; weae = weae1; K = FIN; H = 4; }
  else if (l == 1) { W = w2; as_ = s2; ad_ = d2; We = e2; ae_ = a2; was = was2; wad = wad2; weae = weae2; K = CC; H = 2; }
  else { W = w3; as_ = s3; ad_ = d3; We = e3; ae_ = a3; was = was3; wad = wad3; weae = weae3; K = CC; H = 4; }
  int M = H * CC;
  int tot = 2 * K * H + EDD * H;
  for (int t = threadIdx.x; t < tot; t += 256) {
    if (t < K * H) {
      int k = t / H, h = t % H;
      float s = 0.f;
      for (int c = 0; c < CC; ++c) s += W[(size_t)k * M + h * CC + c] * as_[h * CC + c];
      was[t] = s;
    } else if (t < 2 * K * H) {
      int u = t - K * H;
      int k = u / H, h = u % H;
      float s = 0.f;
      for (int c = 0; c < CC; ++c) s += W[(size_t)k * M + h * CC + c] * ad_[h * CC + c];
      wad[u] = s;
    } else {
      int u = t - 2 * K * H;
      int d = u / H, h = u % H;
      float s = 0.f;
      for (int c = 0; c < CC; ++c) s += We[(size_t)d * M + h * CC + c] * ae_[h * CC + c];
      weae[u] = s;
    }
  }
}

// hierarchical exclusive scan of deg[NN] -> row_off[NN+1]
__global__ __launch_bounds__(256) void k_scan1(const int* __restrict__ deg,
                                               int* __restrict__ row_off,
                                               int* __restrict__ bsum) {
  __shared__ int sm[256];
  int t = threadIdx.x;
  int i = blockIdx.x * 256 + t;
  int v = (i < NN) ? deg[i] : 0;
  sm[t] = v;
  __syncthreads();
  for (int off = 1; off < 256; off <<= 1) {
    int val = (t >= off) ? sm[t - off] : 0;
    __syncthreads();
    sm[t] += val;
    __syncthreads();
  }
  if (i < NN) row_off[i] = sm[t] - v;
  if (t == 255) bsum[blockIdx.x] = sm[255];
}

__global__ __launch_bounds__(256) void k_scan2(int* __restrict__ bsum, int* __restrict__ row_off) {
  __shared__ int sm[256];
  int t = threadIdx.x;
  int v = (t < SCAN_BLK) ? bsum[t] : 0;
  sm[t] = v;
  __syncthreads();
  for (int off = 1; off < 256; off <<= 1) {
    int val = (t >= off) ? sm[t - off] : 0;
    __syncthreads();
    sm[t] += val;
    __syncthreads();
  }
  if (t < SCAN_BLK) bsum[t] = sm[t] - v;
  if (t == 255) row_off[NN] = sm[255];
}

__global__ __launch_bounds__(256) void k_scan3(const int* __restrict__ bsum,
                                               int* __restrict__ row_off) {
  int i = blockIdx.x * 256 + threadIdx.x;
  if (i < NN) row_off[i] += bsum[blockIdx.x];
}

// Fused layer-1 GEMM + CSR fill (independent; complementary pipes).
// __launch_bounds__(256, 4): cap 128 VGPR so the fill branch keeps >=4 blocks/CU
// (unbounded, the compiler pipelined the GEMM K-loop to 208 VGPR -> 9.5% occupancy).
__global__ __launch_bounds__(256, 4) void k_gemm1_fill(
    const float* __restrict__ x, const float* __restrict__ W,
    const float* __restrict__ was, const float* __restrict__ wad,
    h4* __restrict__ xw, float* __restrict__ asrc, float* __restrict__ adst,
    const int* __restrict__ src, const int* __restrict__ dst, const float* __restrict__ ea,
    const int* __restrict__ row_off, int* __restrict__ cursor,
    const float* __restrict__ weae1, const float* __restrict__ weae2,
    const float* __restrict__ weae3, unsigned int* __restrict__ edata) {
  if (blockIdx.x < G1_BLKS) {
    // ---- GEMM path: K=FIN=32, M=256, H=4, no BN ----
    constexpr int K = FIN, M = 256, H = 4, BR = 32;
    constexpr int CG = M / 4;     // 64
    constexpr int RG = 256 / CG;  // 4
    constexpr int R = BR / RG;    // 8
    __shared__ float4 xs4[BR][K / 4];
    int tid = threadIdx.x;
    int rbase = blockIdx.x * BR;
    for (int j = tid; j < BR * K / 4; j += 256) {
      int row = j / (K / 4), kq = j % (K / 4);
      int gr = rbase + row;
      float4 v = {0.f, 0.f, 0.f, 0.f};
      if (gr < NN) v = *(const float4*)(x + (size_t)gr * K + kq * 4);
      xs4[row][kq] = v;
    }
    __syncthreads();
    int cg = tid % CG, rg = tid / CG;
    int col0 = cg * 4;
    float acc[R][4];
#pragma unroll
    for (int r = 0; r < R; ++r)
#pragma unroll
      for (int c = 0; c < 4; ++c) acc[r][c] = 0.f;
    for (int k0 = 0; k0 < K; k0 += 4) {
      float4 wv[4];
#pragma unroll
      for (int kk = 0; kk < 4; ++kk) wv[kk] = *(const float4*)(W + (size_t)(k0 + kk) * M + col0);
#pragma unroll
      for (int r = 0; r < R; ++r) {
        float4 xv = xs4[rg * R + r][k0 / 4];
        const float* xf = (const float*)&xv;
#pragma unroll
        for (int kk = 0; kk < 4; ++kk) {
          const float* wf = (const float*)&wv[kk];
          float xk = xf[kk];
#pragma unroll
          for (int c = 0; c < 4; ++c) acc[r][c] += xk * wf[c];
        }
      }
    }
#pragma unroll
    for (int r = 0; r < R; ++r) {
      int gr = rbase + rg * R + r;
      if (gr < NN) {
        h4 hv;
        hv.x = (_Float16)acc[r][0]; hv.y = (_Float16)acc[r][1];
        hv.z = (_Float16)acc[r][2]; hv.w = (_Float16)acc[r][3];
        xw[(size_t)gr * (M / 4) + cg] = hv;
      }
    }
    if (tid < 2 * BR * H) {
      int which = tid / (BR * H);
      int u = tid % (BR * H);
      int row = u / H, h = u % H;
      int gr = rbase + row;
      if (gr < NN) {
        const float* wv = which ? wad : was;
        const float* xr = (const float*)&xs4[row][0];
        float s = 0.f;
        for (int k = 0; k < K; ++k) s += xr[k] * wv[k * H + h];
        (which ? adst : asrc)[(size_t)gr * H + h] = s;
      }
    }
  } else {
    // ---- FILL path ----
    __shared__ float w1[EDD * 4], w2[EDD * 2], w3[EDD * 4];
    int t = threadIdx.x;
    if (t < 40) w1[t] = weae1[t];
    else if (t < 60) w2[t - 40] = weae2[t - 40];
    else if (t < 100) w3[t - 60] = weae3[t - 60];
    __syncthreads();
    int e = (blockIdx.x - G1_BLKS) * 256 + t;
    if (e >= EE) return;
    int d = dst[e];
    int pos = row_off[d] + atomicAdd(&cursor[d], 1);
    float r[EDD];
    const float* row = ea + (size_t)e * EDD;
#pragma unroll
    for (int i2 = 0; i2 < EDD / 2; ++i2) {
      float2 v = *(const float2*)(row + 2 * i2);
      r[2 * i2] = v.x;
      r[2 * i2 + 1] = v.y;
    }
    float o1[4] = {0, 0, 0, 0}, o2[2] = {0, 0}, o3[4] = {0, 0, 0, 0};
#pragma unroll
    for (int dd = 0; dd < EDD; ++dd) {
      float rv = r[dd];
#pragma unroll
      for (int h = 0; h < 4; ++h) o1[h] += rv * w1[dd * 4 + h];
#pragma unroll
      for (int h = 0; h < 2; ++h) o2[h] += rv * w2[dd * 2 + h];
#pragma unroll
      for (int h = 0; h < 4; ++h) o3[h] += rv * w3[dd * 4 + h];
    }
    uint4 lo;
    lo.x = (unsigned int)src[e];
    lo.y = pack2(o1[0], o1[1]);
    lo.z = pack2(o1[2], o1[3]);
    lo.w = pack2(o2[0], o2[1]);
    uint2 hi;
    hi.x = pack2(o3[0], o3[1]);
    hi.y = pack2(o3[2], o3[3]);
    *(uint4*)(edata + (size_t)pos * 8) = lo;
    *(uint2*)(edata + (size_t)pos * 8 + 4) = hi;
  }
}

// xw(fp16) = [BN(in)] @ W, plus asrc/adst epilogue. BN fused on the staging load.
template <int K, int M, int H, bool BN>
__global__ __launch_bounds__(256) void k_gemm(const float* __restrict__ in, const float* __restrict__ W,
                       const float* __restrict__ was, const float* __restrict__ wad,
                       const float* __restrict__ bnscale, const float* __restrict__ bnshift,
                       h4* __restrict__ xw, float* __restrict__ asrc, float* __restrict__ adst) {
  constexpr int BR = 32;
  constexpr int CG = M / 4;
  constexpr int RG = 256 / CG;
  constexpr int R = BR / RG;
  __shared__ float4 xs4[BR][K / 4];
  int tid = threadIdx.x;
  int rbase = blockIdx.x * BR;
  for (int j = tid; j < BR * K / 4; j += 256) {
    int row = j / (K / 4), kq = j % (K / 4);
    int gr = rbase + row;
    float4 v = {0.f, 0.f, 0.f, 0.f};
    if (gr < NN) v = *(const float4*)(in + (size_t)gr * K + kq * 4);
    if (BN) {
      float4 sc = *(const float4*)(bnscale + kq * 4);
      float4 sh = *(const float4*)(bnshift + kq * 4);
      v.x = fmaxf(v.x * sc.x + sh.x, 0.f);
      v.y = fmaxf(v.y * sc.y + sh.y, 0.f);
      v.z = fmaxf(v.z * sc.z + sh.z, 0.f);
      v.w = fmaxf(v.w * sc.w + sh.w, 0.f);
    }
    xs4[row][kq] = v;
  }
  __syncthreads();
  int cg = tid % CG, rg = tid / CG;
  int col0 = cg * 4;
  float acc[R][4];
#pragma unroll
  for (int r = 0; r < R; ++r)
#pragma unroll
    for (int c = 0; c < 4; ++c) acc[r][c] = 0.f;
  for (int k0 = 0; k0 < K; k0 += 4) {
    float4 wv[4];
#pragma unroll
    for (int kk = 0; kk < 4; ++kk) wv[kk] = *(const float4*)(W + (size_t)(k0 + kk) * M + col0);
#pragma unroll
    for (int r = 0; r < R; ++r) {
      float4 xv = xs4[rg * R + r][k0 / 4];
      const float* xf = (const float*)&xv;
#pragma unroll
      for (int kk = 0; kk < 4; ++kk) {
        const float* wf = (const float*)&wv[kk];
        float xk = xf[kk];
#pragma unroll
        for (int c = 0; c < 4; ++c) acc[r][c] += xk * wf[c];
      }
    }
  }
#pragma unroll
  for (int r = 0; r < R; ++r) {
    int gr = rbase + rg * R + r;
    if (gr < NN) {
      h4 hv;
      hv.x = (_Float16)acc[r][0]; hv.y = (_Float16)acc[r][1];
      hv.z = (_Float16)acc[r][2]; hv.w = (_Float16)acc[r][3];
      xw[(size_t)gr * (M / 4) + cg] = hv;
    }
  }
  if (tid < 2 * BR * H) {
    int which = tid / (BR * H);
    int u = tid % (BR * H);
    int row = u / H, h = u % H;
    int gr = rbase + row;
    if (gr < NN) {
      const float* wv = which ? wad : was;
      const float* xr = (const float*)&xs4[row][0];
      float s = 0.f;
      for (int k = 0; k < K; ++k) s += xr[k] * wv[k * H + h];
      (which ? adst : asrc)[(size_t)gr * H + h] = s;
    }
  }
}

// fused GAT node kernel: 16-lane group per node (4 nodes/wave), h4 gathers.
// lane g owns h4 column g+16q of its node's output -> NO acc reduce.
// Per-edge src+ae in one packed 16B load (layers 1/2) or +8B (layer 3).
// Self-loop logit from running aedge sum (linearity). BN stats fused.
template <int H, int L>
__global__ __launch_bounds__(256) void k_node(const h4* __restrict__ xw,
    const float* __restrict__ asrc, const float* __restrict__ adst,
    const unsigned int* __restrict__ edata, const int* __restrict__ row_off,
    const float* __restrict__ bias,
    float* __restrict__ out, float* __restrict__ psum, float* __restrict__ psum2) {
  constexpr int SH = (H == 4) ? 6 : 5;  // log2(h4 per row)
  int lane = threadIdx.x & 63, wid = threadIdx.x >> 6;
  int grp = lane >> 4, g = lane & 15;
  int grpbase = lane & 48;
  int n = (blockIdx.x * 4 + wid) * 4 + grp;  // grid sized so n < NN always
  int beg = row_off[n], end = row_off[n + 1];
  int deg = end - beg;
  float adh[H], asn[H], dp[H], aes[H];
  float4 acc[H];
#pragma unroll
  for (int h = 0; h < H; ++h) {
    adh[h] = adst[(size_t)n * H + h];
    asn[h] = asrc[(size_t)n * H + h];
    dp[h] = 0.f; aes[h] = 0.f;
    acc[h] = make_float4(0.f, 0.f, 0.f, 0.f);
  }
  for (int cb = beg; cb < end; cb += 16) {
    int i = cb + g;
    float p[H];
    int s = 0;
    if (i < end) {
      uint4 lo = *(const uint4*)(edata + (size_t)i * 8);
      s = (int)lo.x;
      float av[H];
      if (L == 1) {
        float2 a = unpack2(lo.y), b = unpack2(lo.z);
        av[0] = a.x; av[1] = a.y; av[2] = b.x; av[3] = b.y;
      } else if (L == 2) {
        float2 a = unpack2(lo.w);
        av[0] = a.x; av[1] = a.y;
      } else {
        uint2 hi = *(const uint2*)(edata + (size_t)i * 8 + 4);
        float2 a = unpack2(hi.x), b = unpack2(hi.y);
        av[0] = a.x; av[1] = a.y; av[2] = b.x; av[3] = b.y;
      }
      if (H == 4) {
        float4 s4 = *(const float4*)(asrc + (size_t)s * 4);
        p[0] = __expf(lrelu(s4.x + adh[0] + av[0], 0.2f));
        p[1] = __expf(lrelu(s4.y + adh[1] + av[1], 0.2f));
        p[2] = __expf(lrelu(s4.z + adh[2] + av[2], 0.2f));
        p[3] = __expf(lrelu(s4.w + adh[3] + av[3], 0.2f));
      } else {
        float2 s2 = *(const float2*)(asrc + (size_t)s * 2);
        p[0] = __expf(lrelu(s2.x + adh[0] + av[0], 0.2f));
        p[1] = __expf(lrelu(s2.y + adh[1] + av[1], 0.2f));
      }
#pragma unroll
      for (int h = 0; h < H; ++h) { dp[h] += p[h]; aes[h] += av[h]; }
    } else {
#pragma unroll
      for (int h = 0; h < H; ++h) p[h] = 0.f;
    }
    int cnt = min(16, end - cb);
    for (int j = 0; j < cnt; ++j) {
      int sl = grpbase | j;
      int sj = __shfl(s, sl);
      const h4* rb = xw + ((size_t)sj << SH) + g;
#pragma unroll
      for (int q = 0; q < H; ++q) {
        float pj = __shfl(p[q], sl);
        h4 v = rb[16 * q];
        acc[q].x += pj * (float)v.x;
        acc[q].y += pj * (float)v.y;
        acc[q].z += pj * (float)v.z;
        acc[q].w += pj * (float)v.w;
      }
    }
  }
  // reduce dp/aes within the 16-lane group (serves 4 nodes per instruction)
#pragma unroll
  for (int off = 1; off < 16; off <<= 1)
#pragma unroll
    for (int h = 0; h < H; ++h) {
      dp[h] += __shfl_xor(dp[h], off);
      aes[h] += __shfl_xor(aes[h], off);
    }
  float invd = 1.f / (float)max(deg, 1);
  float psv[H];
  const h4* rbs = xw + ((size_t)n << SH) + g;
#pragma unroll
  for (int q = 0; q < H; ++q) {
    psv[q] = __expf(lrelu(asn[q] + adh[q] + aes[q] * invd, 0.2f));
    h4 v = rbs[16 * q];
    acc[q].x += psv[q] * (float)v.x;
    acc[q].y += psv[q] * (float)v.y;
    acc[q].z += psv[q] * (float)v.z;
    acc[q].w += psv[q] * (float)v.w;
  }
  float4 res = *(const float4*)(bias + 4 * g);
#pragma unroll
  for (int q = 0; q < H; ++q) {
    float iv = (1.0f / H) / (dp[q] + psv[q]);
    res.x += acc[q].x * iv;
    res.y += acc[q].y * iv;
    res.z += acc[q].z * iv;
    res.w += acc[q].w * iv;
  }
  *(float4*)(out + (size_t)n * CC + 4 * g) = res;
  // fused BN statistics: block LDS reduce -> 64-slot rotated atomics
  __shared__ float sv[16][64], sq[16][64];
  int row = wid * 4 + grp;
  *(float4*)&sv[row][4 * g] = res;
  float4 r2;
  r2.x = res.x * res.x; r2.y = res.y * res.y; r2.z = res.z * res.z; r2.w = res.w * res.w;
  *(float4*)&sq[row][4 * g] = r2;
  __syncthreads();
  int tid = threadIdx.x;
  if (tid < 128) {
    int c = tid & 63, which = tid >> 6;
    const float(*m)[64] = which ? sq : sv;
    float ssum = 0.f;
#pragma unroll
    for (int r0 = 0; r0 < 16; ++r0) ssum += m[r0][c];
    atomicAdd((which ? psum2 : psum) + ((blockIdx.x & 63) * 64 + c), ssum);
  }
}

__global__ __launch_bounds__(64) void k_bn_final(const float* __restrict__ psum,
                           const float* __restrict__ psum2, const float* __restrict__ g,
                           const float* __restrict__ be, float* __restrict__ scale,
                           float* __restrict__ shift) {
  int c = threadIdx.x;
  float s = 0.f, s2 = 0.f;
  for (int b = 0; b < 64; ++b) {
    s += psum[b * 64 + c];
    s2 += psum2[b * 64 + c];
  }
  float mu = s / (float)NN;
  float var = s2 / (float)NN - mu * mu;
  float sc = g[c] * rsqrtf(var + EPSV);
  scale[c] = sc;
  shift[c] = be[c] - mu * sc;
}

// final layer: BN + leaky_relu + pooled atomicAdd
__global__ __launch_bounds__(256) void k_bn_apply_pool(const float* __restrict__ x,
                                const float* __restrict__ scale, const float* __restrict__ shift,
                                const int* __restrict__ batch, float* __restrict__ pooled) {
  int i = blockIdx.x * blockDim.x + threadIdx.x;
  if (i >= NN * CC) return;
  int nidx = i >> 6, c = i & 63;
  float v = x[i] * scale[c] + shift[c];
  v = lrelu(v, 0.01f);
  atomicAdd(&pooled[batch[nidx] * CC + c], v);
}

__global__ __launch_bounds__(64) void k_head(const float* __restrict__ pooled,
                       const float* __restrict__ gcnt,
                       const float* __restrict__ fw1, const float* __restrict__ fb1,
                       const float* __restrict__ fw2, const float* __restrict__ fb2,
                       float* __restrict__ out) {
  int g = blockIdx.x;
  int j = threadIdx.x;
  float inv = 1.f / fmaxf(gcnt[g], 1.f);
  float h1 = fb1[j];
  for (int k = 0; k < CC; ++k) h1 += (pooled[g * CC + k] * inv) * fw1[k * CC + j];
  h1 = fmaxf(h1, 0.f);
  float o = h1 * fw2[j];
#pragma unroll
  for (int off = 32; off > 0; off >>= 1) o += __shfl_xor(o, off);
  if (j == 0) out[g] = o + fb2[0];
}

// ---------------- launch ----------------
extern "C" void kernel_launch(void* const* d_in, const int* in_sizes, int n_in,
                              void* d_out, int out_size, void* d_ws, size_t ws_size,
                              hipStream_t stream) {
  const float* x = (const float*)d_in[0];
  const int* eidx = (const int*)d_in[1];
  const float* ea = (const float*)d_in[2];
  const int* batch = (const int*)d_in[3];
  const float* w[3] = {(const float*)d_in[4], (const float*)d_in[12], (const float*)d_in[20]};
  const float* as_[3] = {(const float*)d_in[5], (const float*)d_in[13], (const float*)d_in[21]};
  const float* ad_[3] = {(const float*)d_in[6], (const float*)d_in[14], (const float*)d_in[22]};
  const float* we_[3] = {(const float*)d_in[7], (const float*)d_in[15], (const float*)d_in[23]};
  const float* ae_[3] = {(const float*)d_in[8], (const float*)d_in[16], (const float*)d_in[24]};
  const float* b_[3] = {(const float*)d_in[9], (const float*)d_in[17], (const float*)d_in[25]};
  const float* g_[3] = {(const float*)d_in[10], (const float*)d_in[18], (const float*)d_in[26]};
  const float* be_[3] = {(const float*)d_in[11], (const float*)d_in[19], (const float*)d_in[27]};
  const float* fw1 = (const float*)d_in[28];
  const float* fb1 = (const float*)d_in[29];
  const float* fw2 = (const float*)d_in[30];
  const float* fb2 = (const float*)d_in[31];
  const int* srcp = eidx;
  const int* dstp = eidx + EE;

  char* base = (char*)d_ws;
  size_t off = 0;
  auto alloc = [&](size_t bytes) {
    void* p = base + off;
    off = (off + bytes + 255) & ~(size_t)255;
    return p;
  };
  // ---- zero-init region (one memset) ----
  int* deg_i = (int*)alloc((size_t)NN * 4);
  int* cursor = (int*)alloc((size_t)NN * 4);
  float* pooled = (float*)alloc((size_t)GG * CC * 4);
  float* gcnt = (float*)alloc((size_t)GG * 4);
  float* psA1 = (float*)alloc((size_t)64 * 64 * 4);
  float* psB1 = (float*)alloc((size_t)64 * 64 * 4);
  float* psA2 = (float*)alloc((size_t)64 * 64 * 4);
  float* psB2 = (float*)alloc((size_t)64 * 64 * 4);
  float* psA3 = (float*)alloc((size_t)64 * 64 * 4);
  float* psB3 = (float*)alloc((size_t)64 * 64 * 4);
  size_t zero_span = off;
  // ---- rest ----
  int* row_off = (int*)alloc((size_t)(NN + 1) * 4);
  int* bsum = (int*)alloc((size_t)SCAN_BLK * 4);
  unsigned int* edata = (unsigned int*)alloc((size_t)EE * 32);
  float* asrc = (float*)alloc((size_t)NN * 4 * 4);
  float* adst = (float*)alloc((size_t)NN * 4 * 4);
  h4* xw16 = (h4*)alloc((size_t)NN * 256 * 2);
  float* hA = (float*)alloc((size_t)NN * CC * 4);
  float* hB = (float*)alloc((size_t)NN * CC * 4);
  float* bnscale = (float*)alloc(CC * 4);
  float* bnshift = (float*)alloc(CC * 4);
  float* was1 = (float*)alloc((size_t)FIN * 4 * 4);
  float* wad1 = (float*)alloc((size_t)FIN * 4 * 4);
  float* weae1 = (float*)alloc(EDD * 4 * 4);
  float* was2 = (float*)alloc((size_t)CC * 2 * 4);
  float* wad2 = (float*)alloc((size_t)CC * 2 * 4);
  float* weae2 = (float*)alloc(EDD * 2 * 4);
  float* was3 = (float*)alloc((size_t)CC * 4 * 4);
  float* wad3 = (float*)alloc((size_t)CC * 4 * 4);
  float* weae3 = (float*)alloc(EDD * 4 * 4);
  (void)ws_size; (void)in_sizes; (void)n_in; (void)out_size;

  hipMemsetAsync(base, 0, zero_span, stream);

  k_pre_prep<<<PRE_BLKS + 3, 256, 0, stream>>>(
      dstp, batch, deg_i, gcnt,
      w[0], as_[0], ad_[0], we_[0], ae_[0],
      w[1], as_[1], ad_[1], we_[1], ae_[1],
      w[2], as_[2], ad_[2], we_[2], ae_[2],
      was1, wad1, weae1, was2, wad2, weae2, was3, wad3, weae3);
  k_scan1<<<SCAN_BLK, 256, 0, stream>>>(deg_i, row_off, bsum);
  k_scan2<<<1, 256, 0, stream>>>(bsum, row_off);
  k_scan3<<<SCAN_BLK, 256, 0, stream>>>(bsum, row_off);

  // fused: layer-1 GEMM (independent of graph) + CSR fill
  k_gemm1_fill<<<G1_BLKS + PRE_BLKS, 256, 0, stream>>>(
      x, w[0], was1, wad1, xw16, asrc, adst,
      srcp, dstp, ea, row_off, cursor, weae1, weae2, weae3, edata);

  // layer 1 (H=4)
  k_node<4, 1><<<NN / 16, 256, 0, stream>>>(xw16, asrc, adst, edata, row_off, b_[0], hA,
                                            psA1, psB1);
  k_bn_final<<<1, 64, 0, stream>>>(psA1, psB1, g_[0], be_[0], bnscale, bnshift);

  // layer 2 (H=2), BN of layer 1 fused into GEMM staging
  k_gemm<CC, 128, 2, true><<<(NN + 31) / 32, 256, 0, stream>>>(hA, w[1], was2, wad2, bnscale,
                                                               bnshift, xw16, asrc, adst);
  k_node<2, 2><<<NN / 16, 256, 0, stream>>>(xw16, asrc, adst, edata, row_off, b_[1], hB,
                                            psA2, psB2);
  k_bn_final<<<1, 64, 0, stream>>>(psA2, psB2, g_[1], be_[1], bnscale, bnshift);

  // layer 3 (H=4)
  k_gemm<CC, 256, 4, true><<<(NN + 31) / 32, 256, 0, stream>>>(hB, w[2], was3, wad3, bnscale,
                                                               bnshift, xw16, asrc, adst);
  k_node<4, 3><<<NN / 16, 256, 0, stream>>>(xw16, asrc, adst, edata, row_off, b_[2], hA,
                                            psA3, psB3);
  k_bn_final<<<1, 64, 0, stream>>>(psA3, psB3, g_[2], be_[2], bnscale, bnshift);
  k_bn_apply_pool<<<(NN * CC + 255) / 256, 256, 0, stream>>>(hA, bnscale, bnshift, batch, pooled);

  k_head<<<GG, 64, 0, stream>>>(pooled, gcnt, fw1, fb1, fw2, fb2, (float*)d_out);
}

// Round 13
// 426.670 us; speedup vs baseline: 1.6145x; 1.6145x over previous
//
#include <hip/hip_runtime.h>
#include <cstdint>
#include <cstddef>

#define NN 50000
#define EE 800000
#define FIN 32
#define EDD 10
#define GG 512
#define CC 64
#define SCAN_BLK 196        // ceil(NN/256)
#define PRE_BLKS ((EE + 255) / 256)   // 3125
static constexpr float EPSV = 1e-5f;

typedef _Float16 h4 __attribute__((ext_vector_type(4)));
typedef _Float16 h2v __attribute__((ext_vector_type(2)));

union U32H2 { unsigned int u; h2v h; };

__device__ __forceinline__ unsigned int pack2(float a, float b) {
  U32H2 x;
  x.h.x = (_Float16)a;
  x.h.y = (_Float16)b;
  return x.u;
}
__device__ __forceinline__ float2 unpack2(unsigned int u) {
  U32H2 x;
  x.u = u;
  return make_float2((float)x.h.x, (float)x.h.y);
}

__device__ __forceinline__ float lrelu(float x, float s) { return x > 0.f ? x : s * x; }

// ---------------- preprocessing ----------------
// blocks [0, PRE_BLKS): degree count + per-graph node count (atomics, latency-bound)
// blocks [PRE_BLKS, PRE_BLKS+3): per-layer was/wad/weae prep (tiny GEMV, hidden under pre)
__global__ __launch_bounds__(256) void k_pre_prep(
    const int* __restrict__ dst, const int* __restrict__ batch,
    int* __restrict__ deg, float* __restrict__ gcnt,
    const float* __restrict__ w1, const float* __restrict__ s1, const float* __restrict__ d1,
    const float* __restrict__ e1, const float* __restrict__ a1,
    const float* __restrict__ w2, const float* __restrict__ s2, const float* __restrict__ d2,
    const float* __restrict__ e2, const float* __restrict__ a2,
    const float* __restrict__ w3, const float* __restrict__ s3, const float* __restrict__ d3,
    const float* __restrict__ e3, const float* __restrict__ a3,
    float* __restrict__ was1, float* __restrict__ wad1, float* __restrict__ weae1,
    float* __restrict__ was2, float* __restrict__ wad2, float* __restrict__ weae2,
    float* __restrict__ was3, float* __restrict__ wad3, float* __restrict__ weae3) {
  int b = blockIdx.x;
  if (b < PRE_BLKS) {
    int e = b * 256 + threadIdx.x;
    if (e < EE) atomicAdd(&deg[dst[e]], 1);
    if (e < NN) atomicAdd(&gcnt[batch[e]], 1.f);
    return;
  }
  int l = b - PRE_BLKS;
  const float *W, *as_, *ad_, *We, *ae_;
  float *was, *wad, *weae;
  int K, H;
  if (l == 0) { W = w1; as_ = s1; ad_ = d1; We = e1; ae_ = a1; was = was1; wad = wad1; weae = weae1; K = FIN; H = 4; }
  else if (l == 1) { W = w2; as_ = s2; ad_ = d2; We = e2; ae_ = a2; was = was2; wad = wad2; weae = weae2; K = CC; H = 2; }
  else { W = w3; as_ = s3; ad_ = d3; We = e3; ae_ = a3; was = was3; wad = wad3; weae = weae3; K = CC; H = 4; }
  int M = H * CC;
  int tot = 2 * K * H + EDD * H;
  for (int t = threadIdx.x; t < tot; t += 256) {
    if (t < K * H) {
      int k = t / H, h = t % H;
      float s = 0.f;
      for (int c = 0; c < CC; ++c) s += W[(size_t)k * M + h * CC + c] * as_[h * CC + c];
      was[t] = s;
    } else if (t < 2 * K * H) {
      int u = t - K * H;
      int k = u / H, h = u % H;
      float s = 0.f;
      for (int c = 0; c < CC; ++c) s += W[(size_t)k * M + h * CC + c] * ad_[h * CC + c];
      wad[u] = s;
    } else {
      int u = t - 2 * K * H;
      int d = u / H, h = u % H;
      float s = 0.f;
      for (int c = 0; c < CC; ++c) s += We[(size_t)d * M + h * CC + c] * ae_[h * CC + c];
      weae[u] = s;
    }
  }
}

// hierarchical exclusive scan of deg[NN] -> row_off[NN+1]
__global__ __launch_bounds__(256) void k_scan1(const int* __restrict__ deg,
                                               int* __restrict__ row_off,
                                               int* __restrict__ bsum) {
  __shared__ int sm[256];
  int t = threadIdx.x;
  int i = blockIdx.x * 256 + t;
  int v = (i < NN) ? deg[i] : 0;
  sm[t] = v;
  __syncthreads();
  for (int off = 1; off < 256; off <<= 1) {
    int val = (t >= off) ? sm[t - off] : 0;
    __syncthreads();
    sm[t] += val;
    __syncthreads();
  }
  if (i < NN) row_off[i] = sm[t] - v;
  if (t == 255) bsum[blockIdx.x] = sm[255];
}

__global__ __launch_bounds__(256) void k_scan2(int* __restrict__ bsum, int* __restrict__ row_off) {
  __shared__ int sm[256];
  int t = threadIdx.x;
  int v = (t < SCAN_BLK) ? bsum[t] : 0;
  sm[t] = v;
  __syncthreads();
  for (int off = 1; off < 256; off <<= 1) {
    int val = (t >= off) ? sm[t - off] : 0;
    __syncthreads();
    sm[t] += val;
    __syncthreads();
  }
  if (t < SCAN_BLK) bsum[t] = sm[t] - v;
  if (t == 255) row_off[NN] = sm[255];
}

__global__ __launch_bounds__(256) void k_scan3(const int* __restrict__ bsum,
                                               int* __restrict__ row_off) {
  int i = blockIdx.x * 256 + threadIdx.x;
  if (i < NN) row_off[i] += bsum[blockIdx.x];
}

// CSR fill + per-edge attention terms for ALL 3 layers packed into ONE 32B slot per edge:
// edata[pos] = {src, ae1(4xfp16), ae2(2xfp16) | ae3(4xfp16), pad} -> single cacheline scatter.
__global__ __launch_bounds__(256) void k_fill(
    const int* __restrict__ src, const int* __restrict__ dst, const float* __restrict__ ea,
    const int* __restrict__ row_off, int* __restrict__ cursor,
    const float* __restrict__ weae1, const float* __restrict__ weae2,
    const float* __restrict__ weae3, unsigned int* __restrict__ edata) {
  __shared__ float w1[EDD * 4], w2[EDD * 2], w3[EDD * 4];
  int t = threadIdx.x;
  if (t < 40) w1[t] = weae1[t];
  else if (t < 60) w2[t - 40] = weae2[t - 40];
  else if (t < 100) w3[t - 60] = weae3[t - 60];
  __syncthreads();
  int e = blockIdx.x * 256 + t;
  if (e >= EE) return;
  int d = dst[e];
  int pos = row_off[d] + atomicAdd(&cursor[d], 1);
  float r[EDD];
  const float* row = ea + (size_t)e * EDD;
#pragma unroll
  for (int i2 = 0; i2 < EDD / 2; ++i2) {
    float2 v = *(const float2*)(row + 2 * i2);
    r[2 * i2] = v.x;
    r[2 * i2 + 1] = v.y;
  }
  float o1[4] = {0, 0, 0, 0}, o2[2] = {0, 0}, o3[4] = {0, 0, 0, 0};
#pragma unroll
  for (int dd = 0; dd < EDD; ++dd) {
    float rv = r[dd];
#pragma unroll
    for (int h = 0; h < 4; ++h) o1[h] += rv * w1[dd * 4 + h];
#pragma unroll
    for (int h = 0; h < 2; ++h) o2[h] += rv * w2[dd * 2 + h];
#pragma unroll
    for (int h = 0; h < 4; ++h) o3[h] += rv * w3[dd * 4 + h];
  }
  uint4 lo;
  lo.x = (unsigned int)src[e];
  lo.y = pack2(o1[0], o1[1]);
  lo.z = pack2(o1[2], o1[3]);
  lo.w = pack2(o2[0], o2[1]);
  uint2 hi;
  hi.x = pack2(o3[0], o3[1]);
  hi.y = pack2(o3[2], o3[3]);
  *(uint4*)(edata + (size_t)pos * 8) = lo;
  *(uint2*)(edata + (size_t)pos * 8 + 4) = hi;
}

// xw(fp16) = [BN(in)] @ W, plus asrc/adst epilogue. BN fused on the staging load.
template <int K, int M, int H, bool BN>
__global__ __launch_bounds__(256) void k_gemm(const float* __restrict__ in, const float* __restrict__ W,
                       const float* __restrict__ was, const float* __restrict__ wad,
                       const float* __restrict__ bnscale, const float* __restrict__ bnshift,
                       h4* __restrict__ xw, float* __restrict__ asrc, float* __restrict__ adst) {
  constexpr int BR = 32;
  constexpr int CG = M / 4;
  constexpr int RG = 256 / CG;
  constexpr int R = BR / RG;
  __shared__ float4 xs4[BR][K / 4];
  int tid = threadIdx.x;
  int rbase = blockIdx.x * BR;
  for (int j = tid; j < BR * K / 4; j += 256) {
    int row = j / (K / 4), kq = j % (K / 4);
    int gr = rbase + row;
    float4 v = {0.f, 0.f, 0.f, 0.f};
    if (gr < NN) v = *(const float4*)(in + (size_t)gr * K + kq * 4);
    if (BN) {
      float4 sc = *(const float4*)(bnscale + kq * 4);
      float4 sh = *(const float4*)(bnshift + kq * 4);
      v.x = fmaxf(v.x * sc.x + sh.x, 0.f);
      v.y = fmaxf(v.y * sc.y + sh.y, 0.f);
      v.z = fmaxf(v.z * sc.z + sh.z, 0.f);
      v.w = fmaxf(v.w * sc.w + sh.w, 0.f);
    }
    xs4[row][kq] = v;
  }
  __syncthreads();
  int cg = tid % CG, rg = tid / CG;
  int col0 = cg * 4;
  float acc[R][4];
#pragma unroll
  for (int r = 0; r < R; ++r)
#pragma unroll
    for (int c = 0; c < 4; ++c) acc[r][c] = 0.f;
  for (int k0 = 0; k0 < K; k0 += 4) {
    float4 wv[4];
#pragma unroll
    for (int kk = 0; kk < 4; ++kk) wv[kk] = *(const float4*)(W + (size_t)(k0 + kk) * M + col0);
#pragma unroll
    for (int r = 0; r < R; ++r) {
      float4 xv = xs4[rg * R + r][k0 / 4];
      const float* xf = (const float*)&xv;
#pragma unroll
      for (int kk = 0; kk < 4; ++kk) {
        const float* wf = (const float*)&wv[kk];
        float xk = xf[kk];
#pragma unroll
        for (int c = 0; c < 4; ++c) acc[r][c] += xk * wf[c];
      }
    }
  }
#pragma unroll
  for (int r = 0; r < R; ++r) {
    int gr = rbase + rg * R + r;
    if (gr < NN) {
      h4 hv;
      hv.x = (_Float16)acc[r][0]; hv.y = (_Float16)acc[r][1];
      hv.z = (_Float16)acc[r][2]; hv.w = (_Float16)acc[r][3];
      xw[(size_t)gr * (M / 4) + cg] = hv;
    }
  }
  if (tid < 2 * BR * H) {
    int which = tid / (BR * H);
    int u = tid % (BR * H);
    int row = u / H, h = u % H;
    int gr = rbase + row;
    if (gr < NN) {
      const float* wv = which ? wad : was;
      const float* xr = (const float*)&xs4[row][0];
      float s = 0.f;
      for (int k = 0; k < K; ++k) s += xr[k] * wv[k * H + h];
      (which ? adst : asrc)[(size_t)gr * H + h] = s;
    }
  }
}

// fused GAT node kernel: 16-lane group per node (4 nodes/wave), h4 gathers.
// lane g owns h4 column g+16q of its node's output -> NO acc reduce.
// Per-edge src+ae in one packed 16B load (layers 1/2) or +8B (layer 3).
// Self-loop logit from running aedge sum (linearity). BN stats fused.
template <int H, int L>
__global__ __launch_bounds__(256) void k_node(const h4* __restrict__ xw,
    const float* __restrict__ asrc, const float* __restrict__ adst,
    const unsigned int* __restrict__ edata, const int* __restrict__ row_off,
    const float* __restrict__ bias,
    float* __restrict__ out, float* __restrict__ psum, float* __restrict__ psum2) {
  constexpr int SH = (H == 4) ? 6 : 5;  // log2(h4 per row)
  int lane = threadIdx.x & 63, wid = threadIdx.x >> 6;
  int grp = lane >> 4, g = lane & 15;
  int grpbase = lane & 48;
  int n = (blockIdx.x * 4 + wid) * 4 + grp;  // grid sized so n < NN always
  int beg = row_off[n], end = row_off[n + 1];
  int deg = end - beg;
  float adh[H], asn[H], dp[H], aes[H];
  float4 acc[H];
#pragma unroll
  for (int h = 0; h < H; ++h) {
    adh[h] = adst[(size_t)n * H + h];
    asn[h] = asrc[(size_t)n * H + h];
    dp[h] = 0.f; aes[h] = 0.f;
    acc[h] = make_float4(0.f, 0.f, 0.f, 0.f);
  }
  for (int cb = beg; cb < end; cb += 16) {
    int i = cb + g;
    float p[H];
    int s = 0;
    if (i < end) {
      uint4 lo = *(const uint4*)(edata + (size_t)i * 8);
      s = (int)lo.x;
      float av[H];
      if (L == 1) {
        float2 a = unpack2(lo.y), b = unpack2(lo.z);
        av[0] = a.x; av[1] = a.y; av[2] = b.x; av[3] = b.y;
      } else if (L == 2) {
        float2 a = unpack2(lo.w);
        av[0] = a.x; av[1] = a.y;
      } else {
        uint2 hi = *(const uint2*)(edata + (size_t)i * 8 + 4);
        float2 a = unpack2(hi.x), b = unpack2(hi.y);
        av[0] = a.x; av[1] = a.y; av[2] = b.x; av[3] = b.y;
      }
      if (H == 4) {
        float4 s4 = *(const float4*)(asrc + (size_t)s * 4);
        p[0] = __expf(lrelu(s4.x + adh[0] + av[0], 0.2f));
        p[1] = __expf(lrelu(s4.y + adh[1] + av[1], 0.2f));
        p[2] = __expf(lrelu(s4.z + adh[2] + av[2], 0.2f));
        p[3] = __expf(lrelu(s4.w + adh[3] + av[3], 0.2f));
      } else {
        float2 s2 = *(const float2*)(asrc + (size_t)s * 2);
        p[0] = __expf(lrelu(s2.x + adh[0] + av[0], 0.2f));
        p[1] = __expf(lrelu(s2.y + adh[1] + av[1], 0.2f));
      }
#pragma unroll
      for (int h = 0; h < H; ++h) { dp[h] += p[h]; aes[h] += av[h]; }
    } else {
#pragma unroll
      for (int h = 0; h < H; ++h) p[h] = 0.f;
    }
    int cnt = min(16, end - cb);
    for (int j = 0; j < cnt; ++j) {
      int sl = grpbase | j;
      int sj = __shfl(s, sl);
      const h4* rb = xw + ((size_t)sj << SH) + g;
#pragma unroll
      for (int q = 0; q < H; ++q) {
        float pj = __shfl(p[q], sl);
        h4 v = rb[16 * q];
        acc[q].x += pj * (float)v.x;
        acc[q].y += pj * (float)v.y;
        acc[q].z += pj * (float)v.z;
        acc[q].w += pj * (float)v.w;
      }
    }
  }
  // reduce dp/aes within the 16-lane group (serves 4 nodes per instruction)
#pragma unroll
  for (int off = 1; off < 16; off <<= 1)
#pragma unroll
    for (int h = 0; h < H; ++h) {
      dp[h] += __shfl_xor(dp[h], off);
      aes[h] += __shfl_xor(aes[h], off);
    }
  float invd = 1.f / (float)max(deg, 1);
  float psv[H];
  const h4* rbs = xw + ((size_t)n << SH) + g;
#pragma unroll
  for (int q = 0; q < H; ++q) {
    psv[q] = __expf(lrelu(asn[q] + adh[q] + aes[q] * invd, 0.2f));
    h4 v = rbs[16 * q];
    acc[q].x += psv[q] * (float)v.x;
    acc[q].y += psv[q] * (float)v.y;
    acc[q].z += psv[q] * (float)v.z;
    acc[q].w += psv[q] * (float)v.w;
  }
  float4 res = *(const float4*)(bias + 4 * g);
#pragma unroll
  for (int q = 0; q < H; ++q) {
    float iv = (1.0f / H) / (dp[q] + psv[q]);
    res.x += acc[q].x * iv;
    res.y += acc[q].y * iv;
    res.z += acc[q].z * iv;
    res.w += acc[q].w * iv;
  }
  *(float4*)(out + (size_t)n * CC + 4 * g) = res;
  // fused BN statistics: block LDS reduce -> 64-slot rotated atomics
  __shared__ float sv[16][64], sq[16][64];
  int row = wid * 4 + grp;
  *(float4*)&sv[row][4 * g] = res;
  float4 r2;
  r2.x = res.x * res.x; r2.y = res.y * res.y; r2.z = res.z * res.z; r2.w = res.w * res.w;
  *(float4*)&sq[row][4 * g] = r2;
  __syncthreads();
  int tid = threadIdx.x;
  if (tid < 128) {
    int c = tid & 63, which = tid >> 6;
    const float(*m)[64] = which ? sq : sv;
    float ssum = 0.f;
#pragma unroll
    for (int r0 = 0; r0 < 16; ++r0) ssum += m[r0][c];
    atomicAdd((which ? psum2 : psum) + ((blockIdx.x & 63) * 64 + c), ssum);
  }
}

__global__ __launch_bounds__(64) void k_bn_final(const float* __restrict__ psum,
                           const float* __restrict__ psum2, const float* __restrict__ g,
                           const float* __restrict__ be, float* __restrict__ scale,
                           float* __restrict__ shift) {
  int c = threadIdx.x;
  float s = 0.f, s2 = 0.f;
  for (int b = 0; b < 64; ++b) {
    s += psum[b * 64 + c];
    s2 += psum2[b * 64 + c];
  }
  float mu = s / (float)NN;
  float var = s2 / (float)NN - mu * mu;
  float sc = g[c] * rsqrtf(var + EPSV);
  scale[c] = sc;
  shift[c] = be[c] - mu * sc;
}

// final layer: BN + leaky_relu + pooled atomicAdd
__global__ __launch_bounds__(256) void k_bn_apply_pool(const float* __restrict__ x,
                                const float* __restrict__ scale, const float* __restrict__ shift,
                                const int* __restrict__ batch, float* __restrict__ pooled) {
  int i = blockIdx.x * blockDim.x + threadIdx.x;
  if (i >= NN * CC) return;
  int nidx = i >> 6, c = i & 63;
  float v = x[i] * scale[c] + shift[c];
  v = lrelu(v, 0.01f);
  atomicAdd(&pooled[batch[nidx] * CC + c], v);
}

__global__ __launch_bounds__(64) void k_head(const float* __restrict__ pooled,
                       const float* __restrict__ gcnt,
                       const float* __restrict__ fw1, const float* __restrict__ fb1,
                       const float* __restrict__ fw2, const float* __restrict__ fb2,
                       float* __restrict__ out) {
  int g = blockIdx.x;
  int j = threadIdx.x;
  float inv = 1.f / fmaxf(gcnt[g], 1.f);
  float h1 = fb1[j];
  for (int k = 0; k < CC; ++k) h1 += (pooled[g * CC + k] * inv) * fw1[k * CC + j];
  h1 = fmaxf(h1, 0.f);
  float o = h1 * fw2[j];
#pragma unroll
  for (int off = 32; off > 0; off >>= 1) o += __shfl_xor(o, off);
  if (j == 0) out[g] = o + fb2[0];
}

// ---------------- launch ----------------
extern "C" void kernel_launch(void* const* d_in, const int* in_sizes, int n_in,
                              void* d_out, int out_size, void* d_ws, size_t ws_size,
                              hipStream_t stream) {
  const float* x = (const float*)d_in[0];
  const int* eidx = (const int*)d_in[1];
  const float* ea = (const float*)d_in[2];
  const int* batch = (const int*)d_in[3];
  const float* w[3] = {(const float*)d_in[4], (const float*)d_in[12], (const float*)d_in[20]};
  const float* as_[3] = {(const float*)d_in[5], (const float*)d_in[13], (const float*)d_in[21]};
  const float* ad_[3] = {(const float*)d_in[6], (const float*)d_in[14], (const float*)d_in[22]};
  const float* we_[3] = {(const float*)d_in[7], (const float*)d_in[15], (const float*)d_in[23]};
  const float* ae_[3] = {(const float*)d_in[8], (const float*)d_in[16], (const float*)d_in[24]};
  const float* b_[3] = {(const float*)d_in[9], (const float*)d_in[17], (const float*)d_in[25]};
  const float* g_[3] = {(const float*)d_in[10], (const float*)d_in[18], (const float*)d_in[26]};
  const float* be_[3] = {(const float*)d_in[11], (const float*)d_in[19], (const float*)d_in[27]};
  const float* fw1 = (const float*)d_in[28];
  const float* fb1 = (const float*)d_in[29];
  const float* fw2 = (const float*)d_in[30];
  const float* fb2 = (const float*)d_in[31];
  const int* srcp = eidx;
  const int* dstp = eidx + EE;

  char* base = (char*)d_ws;
  size_t off = 0;
  auto alloc = [&](size_t bytes) {
    void* p = base + off;
    off = (off + bytes + 255) & ~(size_t)255;
    return p;
  };
  // ---- zero-init region (one memset) ----
  int* deg_i = (int*)alloc((size_t)NN * 4);
  int* cursor = (int*)alloc((size_t)NN * 4);
  float* pooled = (float*)alloc((size_t)GG * CC * 4);
  float* gcnt = (float*)alloc((size_t)GG * 4);
  float* psA1 = (float*)alloc((size_t)64 * 64 * 4);
  float* psB1 = (float*)alloc((size_t)64 * 64 * 4);
  float* psA2 = (float*)alloc((size_t)64 * 64 * 4);
  float* psB2 = (float*)alloc((size_t)64 * 64 * 4);
  float* psA3 = (float*)alloc((size_t)64 * 64 * 4);
  float* psB3 = (float*)alloc((size_t)64 * 64 * 4);
  size_t zero_span = off;
  // ---- rest ----
  int* row_off = (int*)alloc((size_t)(NN + 1) * 4);
  int* bsum = (int*)alloc((size_t)SCAN_BLK * 4);
  unsigned int* edata = (unsigned int*)alloc((size_t)EE * 32);
  float* asrc = (float*)alloc((size_t)NN * 4 * 4);
  float* adst = (float*)alloc((size_t)NN * 4 * 4);
  h4* xw16 = (h4*)alloc((size_t)NN * 256 * 2);
  float* hA = (float*)alloc((size_t)NN * CC * 4);
  float* hB = (float*)alloc((size_t)NN * CC * 4);
  float* bnscale = (float*)alloc(CC * 4);
  float* bnshift = (float*)alloc(CC * 4);
  float* was1 = (float*)alloc((size_t)FIN * 4 * 4);
  float* wad1 = (float*)alloc((size_t)FIN * 4 * 4);
  float* weae1 = (float*)alloc(EDD * 4 * 4);
  float* was2 = (float*)alloc((size_t)CC * 2 * 4);
  float* wad2 = (float*)alloc((size_t)CC * 2 * 4);
  float* weae2 = (float*)alloc(EDD * 2 * 4);
  float* was3 = (float*)alloc((size_t)CC * 4 * 4);
  float* wad3 = (float*)alloc((size_t)CC * 4 * 4);
  float* weae3 = (float*)alloc(EDD * 4 * 4);
  (void)ws_size; (void)in_sizes; (void)n_in; (void)out_size;

  hipMemsetAsync(base, 0, zero_span, stream);

  k_pre_prep<<<PRE_BLKS + 3, 256, 0, stream>>>(
      dstp, batch, deg_i, gcnt,
      w[0], as_[0], ad_[0], we_[0], ae_[0],
      w[1], as_[1], ad_[1], we_[1], ae_[1],
      w[2], as_[2], ad_[2], we_[2], ae_[2],
      was1, wad1, weae1, was2, wad2, weae2, was3, wad3, weae3);
  k_scan1<<<SCAN_BLK, 256, 0, stream>>>(deg_i, row_off, bsum);
  k_scan2<<<1, 256, 0, stream>>>(bsum, row_off);
  k_scan3<<<SCAN_BLK, 256, 0, stream>>>(bsum, row_off);
  k_fill<<<(EE + 255) / 256, 256, 0, stream>>>(srcp, dstp, ea, row_off, cursor, weae1, weae2,
                                               weae3, edata);

  // layer 1 (H=4)
  k_gemm<FIN, 256, 4, false><<<(NN + 31) / 32, 256, 0, stream>>>(x, w[0], was1, wad1, nullptr,
                                                                 nullptr, xw16, asrc, adst);
  k_node<4, 1><<<NN / 16, 256, 0, stream>>>(xw16, asrc, adst, edata, row_off, b_[0], hA,
                                            psA1, psB1);
  k_bn_final<<<1, 64, 0, stream>>>(psA1, psB1, g_[0], be_[0], bnscale, bnshift);

  // layer 2 (H=2), BN of layer 1 fused into GEMM staging
  k_gemm<CC, 128, 2, true><<<(NN + 31) / 32, 256, 0, stream>>>(hA, w[1], was2, wad2, bnscale,
                                                               bnshift, xw16, asrc, adst);
  k_node<2, 2><<<NN / 16, 256, 0, stream>>>(xw16, asrc, adst, edata, row_off, b_[1], hB,
                                            psA2, psB2);
  k_bn_final<<<1, 64, 0, stream>>>(psA2, psB2, g_[1], be_[1], bnscale, bnshift);

  // layer 3 (H=4)
  k_gemm<CC, 256, 4, true><<<(NN + 31) / 32, 256, 0, stream>>>(hB, w[2], was3, wad3, bnscale,
                                                               bnshift, xw16, asrc, adst);
  k_node<4, 3><<<NN / 16, 256, 0, stream>>>(xw16, asrc, adst, edata, row_off, b_[2], hA,
                                            psA3, psB3);
  k_bn_final<<<1, 64, 0, stream>>>(psA3, psB3, g_[2], be_[2], bnscale, bnshift);
  k_bn_apply_pool<<<(NN * CC + 255) / 256, 256, 0, stream>>>(hA, bnscale, bnshift, batch, pooled);

  k_head<<<GG, 64, 0, stream>>>(pooled, gcnt, fw1, fb1, fw2, fb2, (float*)d_out);
}

// Round 14
// 425.854 us; speedup vs baseline: 1.6175x; 1.0019x over previous
//
#include <hip/hip_runtime.h>
#include <cstdint>
#include <cstddef>

#define NN 50000
#define EE 800000
#define FIN 32
#define EDD 10
#define GG 512
#define CC 64
#define SCAN_BLK 196        // ceil(NN/256)
#define PRE_BLKS ((EE + 255) / 256)   // 3125
static constexpr float EPSV = 1e-5f;

typedef _Float16 h4 __attribute__((ext_vector_type(4)));
typedef _Float16 h2v __attribute__((ext_vector_type(2)));

union U32H2 { unsigned int u; h2v h; };

__device__ __forceinline__ unsigned int pack2(float a, float b) {
  U32H2 x;
  x.h.x = (_Float16)a;
  x.h.y = (_Float16)b;
  return x.u;
}
__device__ __forceinline__ float2 unpack2(unsigned int u) {
  U32H2 x;
  x.u = u;
  return make_float2((float)x.h.x, (float)x.h.y);
}

__device__ __forceinline__ float lrelu(float x, float s) { return x > 0.f ? x : s * x; }

// compute BN scale/shift into LDS from 64-slot partial sums (redundant per block; L2-hit)
__device__ __forceinline__ void bn_to_lds(const float* __restrict__ psum,
                                          const float* __restrict__ psum2,
                                          const float* __restrict__ gamma,
                                          const float* __restrict__ beta,
                                          float* s_sc, float* s_sh, int tid) {
  if (tid < CC) {
    float s = 0.f, s2 = 0.f;
#pragma unroll 8
    for (int b = 0; b < 64; ++b) {
      s += psum[b * 64 + tid];
      s2 += psum2[b * 64 + tid];
    }
    float mu = s / (float)NN;
    float var = s2 / (float)NN - mu * mu;
    float sc = gamma[tid] * rsqrtf(var + EPSV);
    s_sc[tid] = sc;
    s_sh[tid] = beta[tid] - mu * sc;
  }
}

// ---------------- preprocessing ----------------
// blocks [0, PRE_BLKS): degree count + per-graph node count (atomics, latency-bound)
// blocks [PRE_BLKS, PRE_BLKS+3): per-layer was/wad/weae prep (tiny GEMV, hidden under pre)
__global__ __launch_bounds__(256) void k_pre_prep(
    const int* __restrict__ dst, const int* __restrict__ batch,
    int* __restrict__ deg, float* __restrict__ gcnt,
    const float* __restrict__ w1, const float* __restrict__ s1, const float* __restrict__ d1,
    const float* __restrict__ e1, const float* __restrict__ a1,
    const float* __restrict__ w2, const float* __restrict__ s2, const float* __restrict__ d2,
    const float* __restrict__ e2, const float* __restrict__ a2,
    const float* __restrict__ w3, const float* __restrict__ s3, const float* __restrict__ d3,
    const float* __restrict__ e3, const float* __restrict__ a3,
    float* __restrict__ was1, float* __restrict__ wad1, float* __restrict__ weae1,
    float* __restrict__ was2, float* __restrict__ wad2, float* __restrict__ weae2,
    float* __restrict__ was3, float* __restrict__ wad3, float* __restrict__ weae3) {
  int b = blockIdx.x;
  if (b < PRE_BLKS) {
    int e = b * 256 + threadIdx.x;
    if (e < EE) atomicAdd(&deg[dst[e]], 1);
    if (e < NN) atomicAdd(&gcnt[batch[e]], 1.f);
    return;
  }
  int l = b - PRE_BLKS;
  const float *W, *as_, *ad_, *We, *ae_;
  float *was, *wad, *weae;
  int K, H;
  if (l == 0) { W = w1; as_ = s1; ad_ = d1; We = e1; ae_ = a1; was = was1; wad = wad1; weae = weae1; K = FIN; H = 4; }
  else if (l == 1) { W = w2; as_ = s2; ad_ = d2; We = e2; ae_ = a2; was = was2; wad = wad2; weae = weae2; K = CC; H = 2; }
  else { W = w3; as_ = s3; ad_ = d3; We = e3; ae_ = a3; was = was3; wad = wad3; weae = weae3; K = CC; H = 4; }
  int M = H * CC;
  int tot = 2 * K * H + EDD * H;
  for (int t = threadIdx.x; t < tot; t += 256) {
    if (t < K * H) {
      int k = t / H, h = t % H;
      float s = 0.f;
      for (int c = 0; c < CC; ++c) s += W[(size_t)k * M + h * CC + c] * as_[h * CC + c];
      was[t] = s;
    } else if (t < 2 * K * H) {
      int u = t - K * H;
      int k = u / H, h = u % H;
      float s = 0.f;
      for (int c = 0; c < CC; ++c) s += W[(size_t)k * M + h * CC + c] * ad_[h * CC + c];
      wad[u] = s;
    } else {
      int u = t - 2 * K * H;
      int d = u / H, h = u % H;
      float s = 0.f;
      for (int c = 0; c < CC; ++c) s += We[(size_t)d * M + h * CC + c] * ae_[h * CC + c];
      weae[u] = s;
    }
  }
}

// hierarchical exclusive scan of deg[NN] -> row_off[NN+1]
__global__ __launch_bounds__(256) void k_scan1(const int* __restrict__ deg,
                                               int* __restrict__ row_off,
                                               int* __restrict__ bsum) {
  __shared__ int sm[256];
  int t = threadIdx.x;
  int i = blockIdx.x * 256 + t;
  int v = (i < NN) ? deg[i] : 0;
  sm[t] = v;
  __syncthreads();
  for (int off = 1; off < 256; off <<= 1) {
    int val = (t >= off) ? sm[t - off] : 0;
    __syncthreads();
    sm[t] += val;
    __syncthreads();
  }
  if (i < NN) row_off[i] = sm[t] - v;
  if (t == 255) bsum[blockIdx.x] = sm[255];
}

__global__ __launch_bounds__(256) void k_scan2(int* __restrict__ bsum, int* __restrict__ row_off) {
  __shared__ int sm[256];
  int t = threadIdx.x;
  int v = (t < SCAN_BLK) ? bsum[t] : 0;
  sm[t] = v;
  __syncthreads();
  for (int off = 1; off < 256; off <<= 1) {
    int val = (t >= off) ? sm[t - off] : 0;
    __syncthreads();
    sm[t] += val;
    __syncthreads();
  }
  if (t < SCAN_BLK) bsum[t] = sm[t] - v;
  if (t == 255) row_off[NN] = sm[255];
}

__global__ __launch_bounds__(256) void k_scan3(const int* __restrict__ bsum,
                                               int* __restrict__ row_off) {
  int i = blockIdx.x * 256 + threadIdx.x;
  if (i < NN) row_off[i] += bsum[blockIdx.x];
}

// CSR fill + per-edge attention terms for ALL 3 layers packed into ONE 32B slot per edge:
// edata[pos] = {src, ae1(4xfp16), ae2(2xfp16) | ae3(4xfp16), pad} -> single cacheline scatter.
__global__ __launch_bounds__(256) void k_fill(
    const int* __restrict__ src, const int* __restrict__ dst, const float* __restrict__ ea,
    const int* __restrict__ row_off, int* __restrict__ cursor,
    const float* __restrict__ weae1, const float* __restrict__ weae2,
    const float* __restrict__ weae3, unsigned int* __restrict__ edata) {
  __shared__ float w1[EDD * 4], w2[EDD * 2], w3[EDD * 4];
  int t = threadIdx.x;
  if (t < 40) w1[t] = weae1[t];
  else if (t < 60) w2[t - 40] = weae2[t - 40];
  else if (t < 100) w3[t - 60] = weae3[t - 60];
  __syncthreads();
  int e = blockIdx.x * 256 + t;
  if (e >= EE) return;
  int d = dst[e];
  int pos = row_off[d] + atomicAdd(&cursor[d], 1);
  float r[EDD];
  const float* row = ea + (size_t)e * EDD;
#pragma unroll
  for (int i2 = 0; i2 < EDD / 2; ++i2) {
    float2 v = *(const float2*)(row + 2 * i2);
    r[2 * i2] = v.x;
    r[2 * i2 + 1] = v.y;
  }
  float o1[4] = {0, 0, 0, 0}, o2[2] = {0, 0}, o3[4] = {0, 0, 0, 0};
#pragma unroll
  for (int dd = 0; dd < EDD; ++dd) {
    float rv = r[dd];
#pragma unroll
    for (int h = 0; h < 4; ++h) o1[h] += rv * w1[dd * 4 + h];
#pragma unroll
    for (int h = 0; h < 2; ++h) o2[h] += rv * w2[dd * 2 + h];
#pragma unroll
    for (int h = 0; h < 4; ++h) o3[h] += rv * w3[dd * 4 + h];
  }
  uint4 lo;
  lo.x = (unsigned int)src[e];
  lo.y = pack2(o1[0], o1[1]);
  lo.z = pack2(o1[2], o1[3]);
  lo.w = pack2(o2[0], o2[1]);
  uint2 hi;
  hi.x = pack2(o3[0], o3[1]);
  hi.y = pack2(o3[2], o3[3]);
  *(uint4*)(edata + (size_t)pos * 8) = lo;
  *(uint2*)(edata + (size_t)pos * 8 + 4) = hi;
}

// xw(fp16) = [BN(in)] @ W, plus asrc/adst epilogue.
// BN scale/shift computed per block from psum partials (fused bn_final).
template <int K, int M, int H, bool BN>
__global__ __launch_bounds__(256) void k_gemm(const float* __restrict__ in, const float* __restrict__ W,
                       const float* __restrict__ was, const float* __restrict__ wad,
                       const float* __restrict__ psum, const float* __restrict__ psum2,
                       const float* __restrict__ gamma, const float* __restrict__ beta,
                       h4* __restrict__ xw, float* __restrict__ asrc, float* __restrict__ adst) {
  constexpr int BR = 32;
  constexpr int CG = M / 4;
  constexpr int RG = 256 / CG;
  constexpr int R = BR / RG;
  __shared__ float4 xs4[BR][K / 4];
  __shared__ float s_sc[CC], s_sh[CC];
  int tid = threadIdx.x;
  if (BN) {
    bn_to_lds(psum, psum2, gamma, beta, s_sc, s_sh, tid);
    __syncthreads();
  }
  int rbase = blockIdx.x * BR;
  for (int j = tid; j < BR * K / 4; j += 256) {
    int row = j / (K / 4), kq = j % (K / 4);
    int gr = rbase + row;
    float4 v = {0.f, 0.f, 0.f, 0.f};
    if (gr < NN) v = *(const float4*)(in + (size_t)gr * K + kq * 4);
    if (BN) {
      v.x = fmaxf(v.x * s_sc[kq * 4 + 0] + s_sh[kq * 4 + 0], 0.f);
      v.y = fmaxf(v.y * s_sc[kq * 4 + 1] + s_sh[kq * 4 + 1], 0.f);
      v.z = fmaxf(v.z * s_sc[kq * 4 + 2] + s_sh[kq * 4 + 2], 0.f);
      v.w = fmaxf(v.w * s_sc[kq * 4 + 3] + s_sh[kq * 4 + 3], 0.f);
    }
    xs4[row][kq] = v;
  }
  __syncthreads();
  int cg = tid % CG, rg = tid / CG;
  int col0 = cg * 4;
  float acc[R][4];
#pragma unroll
  for (int r = 0; r < R; ++r)
#pragma unroll
    for (int c = 0; c < 4; ++c) acc[r][c] = 0.f;
  for (int k0 = 0; k0 < K; k0 += 4) {
    float4 wv[4];
#pragma unroll
    for (int kk = 0; kk < 4; ++kk) wv[kk] = *(const float4*)(W + (size_t)(k0 + kk) * M + col0);
#pragma unroll
    for (int r = 0; r < R; ++r) {
      float4 xv = xs4[rg * R + r][k0 / 4];
      const float* xf = (const float*)&xv;
#pragma unroll
      for (int kk = 0; kk < 4; ++kk) {
        const float* wf = (const float*)&wv[kk];
        float xk = xf[kk];
#pragma unroll
        for (int c = 0; c < 4; ++c) acc[r][c] += xk * wf[c];
      }
    }
  }
#pragma unroll
  for (int r = 0; r < R; ++r) {
    int gr = rbase + rg * R + r;
    if (gr < NN) {
      h4 hv;
      hv.x = (_Float16)acc[r][0]; hv.y = (_Float16)acc[r][1];
      hv.z = (_Float16)acc[r][2]; hv.w = (_Float16)acc[r][3];
      xw[(size_t)gr * (M / 4) + cg] = hv;
    }
  }
  if (tid < 2 * BR * H) {
    int which = tid / (BR * H);
    int u = tid % (BR * H);
    int row = u / H, h = u % H;
    int gr = rbase + row;
    if (gr < NN) {
      const float* wv = which ? wad : was;
      const float* xr = (const float*)&xs4[row][0];
      float s = 0.f;
      for (int k = 0; k < K; ++k) s += xr[k] * wv[k * H + h];
      (which ? adst : asrc)[(size_t)gr * H + h] = s;
    }
  }
}

// fused GAT node kernel: 16-lane group per node (4 nodes/wave), h4 gathers.
// lane g owns h4 column g+16q of its node's output -> NO acc reduce.
// Per-edge src+ae in one packed 16B load (layers 1/2) or +8B (layer 3).
// Self-loop logit from running aedge sum (linearity). BN stats fused.
template <int H, int L>
__global__ __launch_bounds__(256) void k_node(const h4* __restrict__ xw,
    const float* __restrict__ asrc, const float* __restrict__ adst,
    const unsigned int* __restrict__ edata, const int* __restrict__ row_off,
    const float* __restrict__ bias,
    float* __restrict__ out, float* __restrict__ psum, float* __restrict__ psum2) {
  constexpr int SH = (H == 4) ? 6 : 5;  // log2(h4 per row)
  int lane = threadIdx.x & 63, wid = threadIdx.x >> 6;
  int grp = lane >> 4, g = lane & 15;
  int grpbase = lane & 48;
  int n = (blockIdx.x * 4 + wid) * 4 + grp;  // grid sized so n < NN always
  int beg = row_off[n], end = row_off[n + 1];
  int deg = end - beg;
  float adh[H], asn[H], dp[H], aes[H];
  float4 acc[H];
#pragma unroll
  for (int h = 0; h < H; ++h) {
    adh[h] = adst[(size_t)n * H + h];
    asn[h] = asrc[(size_t)n * H + h];
    dp[h] = 0.f; aes[h] = 0.f;
    acc[h] = make_float4(0.f, 0.f, 0.f, 0.f);
  }
  for (int cb = beg; cb < end; cb += 16) {
    int i = cb + g;
    float p[H];
    int s = 0;
    if (i < end) {
      uint4 lo = *(const uint4*)(edata + (size_t)i * 8);
      s = (int)lo.x;
      float av[H];
      if (L == 1) {
        float2 a = unpack2(lo.y), b = unpack2(lo.z);
        av[0] = a.x; av[1] = a.y; av[2] = b.x; av[3] = b.y;
      } else if (L == 2) {
        float2 a = unpack2(lo.w);
        av[0] = a.x; av[1] = a.y;
      } else {
        uint2 hi = *(const uint2*)(edata + (size_t)i * 8 + 4);
        float2 a = unpack2(hi.x), b = unpack2(hi.y);
        av[0] = a.x; av[1] = a.y; av[2] = b.x; av[3] = b.y;
      }
      if (H == 4) {
        float4 s4 = *(const float4*)(asrc + (size_t)s * 4);
        p[0] = __expf(lrelu(s4.x + adh[0] + av[0], 0.2f));
        p[1] = __expf(lrelu(s4.y + adh[1] + av[1], 0.2f));
        p[2] = __expf(lrelu(s4.z + adh[2] + av[2], 0.2f));
        p[3] = __expf(lrelu(s4.w + adh[3] + av[3], 0.2f));
      } else {
        float2 s2 = *(const float2*)(asrc + (size_t)s * 2);
        p[0] = __expf(lrelu(s2.x + adh[0] + av[0], 0.2f));
        p[1] = __expf(lrelu(s2.y + adh[1] + av[1], 0.2f));
      }
#pragma unroll
      for (int h = 0; h < H; ++h) { dp[h] += p[h]; aes[h] += av[h]; }
    } else {
#pragma unroll
      for (int h = 0; h < H; ++h) p[h] = 0.f;
    }
    int cnt = min(16, end - cb);
    for (int j = 0; j < cnt; ++j) {
      int sl = grpbase | j;
      int sj = __shfl(s, sl);
      const h4* rb = xw + ((size_t)sj << SH) + g;
#pragma unroll
      for (int q = 0; q < H; ++q) {
        float pj = __shfl(p[q], sl);
        h4 v = rb[16 * q];
        acc[q].x += pj * (float)v.x;
        acc[q].y += pj * (float)v.y;
        acc[q].z += pj * (float)v.z;
        acc[q].w += pj * (float)v.w;
      }
    }
  }
  // reduce dp/aes within the 16-lane group (serves 4 nodes per instruction)
#pragma unroll
  for (int off = 1; off < 16; off <<= 1)
#pragma unroll
    for (int h = 0; h < H; ++h) {
      dp[h] += __shfl_xor(dp[h], off);
      aes[h] += __shfl_xor(aes[h], off);
    }
  float invd = 1.f / (float)max(deg, 1);
  float psv[H];
  const h4* rbs = xw + ((size_t)n << SH) + g;
#pragma unroll
  for (int q = 0; q < H; ++q) {
    psv[q] = __expf(lrelu(asn[q] + adh[q] + aes[q] * invd, 0.2f));
    h4 v = rbs[16 * q];
    acc[q].x += psv[q] * (float)v.x;
    acc[q].y += psv[q] * (float)v.y;
    acc[q].z += psv[q] * (float)v.z;
    acc[q].w += psv[q] * (float)v.w;
  }
  float4 res = *(const float4*)(bias + 4 * g);
#pragma unroll
  for (int q = 0; q < H; ++q) {
    float iv = (1.0f / H) / (dp[q] + psv[q]);
    res.x += acc[q].x * iv;
    res.y += acc[q].y * iv;
    res.z += acc[q].z * iv;
    res.w += acc[q].w * iv;
  }
  *(float4*)(out + (size_t)n * CC + 4 * g) = res;
  // fused BN statistics: block LDS reduce -> 64-slot rotated atomics
  __shared__ float sv[16][64], sq[16][64];
  int row = wid * 4 + grp;
  *(float4*)&sv[row][4 * g] = res;
  float4 r2;
  r2.x = res.x * res.x; r2.y = res.y * res.y; r2.z = res.z * res.z; r2.w = res.w * res.w;
  *(float4*)&sq[row][4 * g] = r2;
  __syncthreads();
  int tid = threadIdx.x;
  if (tid < 128) {
    int c = tid & 63, which = tid >> 6;
    const float(*m)[64] = which ? sq : sv;
    float ssum = 0.f;
#pragma unroll
    for (int r0 = 0; r0 < 16; ++r0) ssum += m[r0][c];
    atomicAdd((which ? psum2 : psum) + ((blockIdx.x & 63) * 64 + c), ssum);
  }
}

// final layer: BN (scale/shift computed in-block) + leaky_relu + pooled atomicAdd.
// grid-stride with 1024 blocks to bound the redundant BN-final computation.
__global__ __launch_bounds__(256) void k_bn_apply_pool(const float* __restrict__ x,
                                const float* __restrict__ psum, const float* __restrict__ psum2,
                                const float* __restrict__ gamma, const float* __restrict__ beta,
                                const int* __restrict__ batch, float* __restrict__ pooled) {
  __shared__ float s_sc[CC], s_sh[CC];
  int tid = threadIdx.x;
  bn_to_lds(psum, psum2, gamma, beta, s_sc, s_sh, tid);
  __syncthreads();
  for (int i = blockIdx.x * 256 + tid; i < NN * CC; i += gridDim.x * 256) {
    int nidx = i >> 6, c = i & 63;
    float v = x[i] * s_sc[c] + s_sh[c];
    v = lrelu(v, 0.01f);
    atomicAdd(&pooled[batch[nidx] * CC + c], v);
  }
}

__global__ __launch_bounds__(64) void k_head(const float* __restrict__ pooled,
                       const float* __restrict__ gcnt,
                       const float* __restrict__ fw1, const float* __restrict__ fb1,
                       const float* __restrict__ fw2, const float* __restrict__ fb2,
                       float* __restrict__ out) {
  int g = blockIdx.x;
  int j = threadIdx.x;
  float inv = 1.f / fmaxf(gcnt[g], 1.f);
  float h1 = fb1[j];
  for (int k = 0; k < CC; ++k) h1 += (pooled[g * CC + k] * inv) * fw1[k * CC + j];
  h1 = fmaxf(h1, 0.f);
  float o = h1 * fw2[j];
#pragma unroll
  for (int off = 32; off > 0; off >>= 1) o += __shfl_xor(o, off);
  if (j == 0) out[g] = o + fb2[0];
}

// ---------------- launch ----------------
extern "C" void kernel_launch(void* const* d_in, const int* in_sizes, int n_in,
                              void* d_out, int out_size, void* d_ws, size_t ws_size,
                              hipStream_t stream) {
  const float* x = (const float*)d_in[0];
  const int* eidx = (const int*)d_in[1];
  const float* ea = (const float*)d_in[2];
  const int* batch = (const int*)d_in[3];
  const float* w[3] = {(const float*)d_in[4], (const float*)d_in[12], (const float*)d_in[20]};
  const float* as_[3] = {(const float*)d_in[5], (const float*)d_in[13], (const float*)d_in[21]};
  const float* ad_[3] = {(const float*)d_in[6], (const float*)d_in[14], (const float*)d_in[22]};
  const float* we_[3] = {(const float*)d_in[7], (const float*)d_in[15], (const float*)d_in[23]};
  const float* ae_[3] = {(const float*)d_in[8], (const float*)d_in[16], (const float*)d_in[24]};
  const float* b_[3] = {(const float*)d_in[9], (const float*)d_in[17], (const float*)d_in[25]};
  const float* g_[3] = {(const float*)d_in[10], (const float*)d_in[18], (const float*)d_in[26]};
  const float* be_[3] = {(const float*)d_in[11], (const float*)d_in[19], (const float*)d_in[27]};
  const float* fw1 = (const float*)d_in[28];
  const float* fb1 = (const float*)d_in[29];
  const float* fw2 = (const float*)d_in[30];
  const float* fb2 = (const float*)d_in[31];
  const int* srcp = eidx;
  const int* dstp = eidx + EE;

  char* base = (char*)d_ws;
  size_t off = 0;
  auto alloc = [&](size_t bytes) {
    void* p = base + off;
    off = (off + bytes + 255) & ~(size_t)255;
    return p;
  };
  // ---- zero-init region (one memset) ----
  int* deg_i = (int*)alloc((size_t)NN * 4);
  int* cursor = (int*)alloc((size_t)NN * 4);
  float* pooled = (float*)alloc((size_t)GG * CC * 4);
  float* gcnt = (float*)alloc((size_t)GG * 4);
  float* psA1 = (float*)alloc((size_t)64 * 64 * 4);
  float* psB1 = (float*)alloc((size_t)64 * 64 * 4);
  float* psA2 = (float*)alloc((size_t)64 * 64 * 4);
  float* psB2 = (float*)alloc((size_t)64 * 64 * 4);
  float* psA3 = (float*)alloc((size_t)64 * 64 * 4);
  float* psB3 = (float*)alloc((size_t)64 * 64 * 4);
  size_t zero_span = off;
  // ---- rest ----
  int* row_off = (int*)alloc((size_t)(NN + 1) * 4);
  int* bsum = (int*)alloc((size_t)SCAN_BLK * 4);
  unsigned int* edata = (unsigned int*)alloc((size_t)EE * 32);
  float* asrc = (float*)alloc((size_t)NN * 4 * 4);
  float* adst = (float*)alloc((size_t)NN * 4 * 4);
  h4* xw16 = (h4*)alloc((size_t)NN * 256 * 2);
  float* hA = (float*)alloc((size_t)NN * CC * 4);
  float* hB = (float*)alloc((size_t)NN * CC * 4);
  float* was1 = (float*)alloc((size_t)FIN * 4 * 4);
  float* wad1 = (float*)alloc((size_t)FIN * 4 * 4);
  float* weae1 = (float*)alloc(EDD * 4 * 4);
  float* was2 = (float*)alloc((size_t)CC * 2 * 4);
  float* wad2 = (float*)alloc((size_t)CC * 2 * 4);
  float* weae2 = (float*)alloc(EDD * 2 * 4);
  float* was3 = (float*)alloc((size_t)CC * 4 * 4);
  float* wad3 = (float*)alloc((size_t)CC * 4 * 4);
  float* weae3 = (float*)alloc(EDD * 4 * 4);
  (void)ws_size; (void)in_sizes; (void)n_in; (void)out_size;

  hipMemsetAsync(base, 0, zero_span, stream);

  k_pre_prep<<<PRE_BLKS + 3, 256, 0, stream>>>(
      dstp, batch, deg_i, gcnt,
      w[0], as_[0], ad_[0], we_[0], ae_[0],
      w[1], as_[1], ad_[1], we_[1], ae_[1],
      w[2], as_[2], ad_[2], we_[2], ae_[2],
      was1, wad1, weae1, was2, wad2, weae2, was3, wad3, weae3);
  k_scan1<<<SCAN_BLK, 256, 0, stream>>>(deg_i, row_off, bsum);
  k_scan2<<<1, 256, 0, stream>>>(bsum, row_off);
  k_scan3<<<SCAN_BLK, 256, 0, stream>>>(bsum, row_off);
  k_fill<<<(EE + 255) / 256, 256, 0, stream>>>(srcp, dstp, ea, row_off, cursor, weae1, weae2,
                                               weae3, edata);

  // layer 1 (H=4)
  k_gemm<FIN, 256, 4, false><<<(NN + 31) / 32, 256, 0, stream>>>(
      x, w[0], was1, wad1, nullptr, nullptr, nullptr, nullptr, xw16, asrc, adst);
  k_node<4, 1><<<NN / 16, 256, 0, stream>>>(xw16, asrc, adst, edata, row_off, b_[0], hA,
                                            psA1, psB1);

  // layer 2 (H=2), BN of layer 1 fused into GEMM staging (bn_final computed per block)
  k_gemm<CC, 128, 2, true><<<(NN + 31) / 32, 256, 0, stream>>>(
      hA, w[1], was2, wad2, psA1, psB1, g_[0], be_[0], xw16, asrc, adst);
  k_node<2, 2><<<NN / 16, 256, 0, stream>>>(xw16, asrc, adst, edata, row_off, b_[1], hB,
                                            psA2, psB2);

  // layer 3 (H=4)
  k_gemm<CC, 256, 4, true><<<(NN + 31) / 32, 256, 0, stream>>>(
      hB, w[2], was3, wad3, psA2, psB2, g_[1], be_[1], xw16, asrc, adst);
  k_node<4, 3><<<NN / 16, 256, 0, stream>>>(xw16, asrc, adst, edata, row_off, b_[2], hA,
                                            psA3, psB3);

  // final BN (in-block) + leaky_relu + pool
  k_bn_apply_pool<<<1024, 256, 0, stream>>>(hA, psA3, psB3, g_[2], be_[2], batch, pooled);

  k_head<<<GG, 64, 0, stream>>>(pooled, gcnt, fw1, fb1, fw2, fb2, (float*)d_out);
}

// Round 15
// 406.907 us; speedup vs baseline: 1.6929x; 1.0466x over previous
//
#include <hip/hip_runtime.h>
#include <cstdint>
#include <cstddef>

#define NN 50000
#define EE 800000
#define FIN 32
#define EDD 10
#define GG 512
#define CC 64
#define SCAN_BLK 196        // ceil(NN/256)
#define PRE_BLKS ((EE + 255) / 256)   // 3125
static constexpr float EPSV = 1e-5f;

typedef _Float16 h4 __attribute__((ext_vector_type(4)));
typedef _Float16 h2v __attribute__((ext_vector_type(2)));

union U32H2 { unsigned int u; h2v h; };

__device__ __forceinline__ unsigned int pack2(float a, float b) {
  U32H2 x;
  x.h.x = (_Float16)a;
  x.h.y = (_Float16)b;
  return x.u;
}
__device__ __forceinline__ float2 unpack2(unsigned int u) {
  U32H2 x;
  x.u = u;
  return make_float2((float)x.h.x, (float)x.h.y);
}

__device__ __forceinline__ float lrelu(float x, float s) { return x > 0.f ? x : s * x; }

// compute BN scale/shift into LDS from 64-slot partial sums (redundant per block; L2-hit)
__device__ __forceinline__ void bn_to_lds(const float* __restrict__ psum,
                                          const float* __restrict__ psum2,
                                          const float* __restrict__ gamma,
                                          const float* __restrict__ beta,
                                          float* s_sc, float* s_sh, int tid) {
  if (tid < CC) {
    float s = 0.f, s2 = 0.f;
#pragma unroll 8
    for (int b = 0; b < 64; ++b) {
      s += psum[b * 64 + tid];
      s2 += psum2[b * 64 + tid];
    }
    float mu = s / (float)NN;
    float var = s2 / (float)NN - mu * mu;
    float sc = gamma[tid] * rsqrtf(var + EPSV);
    s_sc[tid] = sc;
    s_sh[tid] = beta[tid] - mu * sc;
  }
}

// ---------------- preprocessing ----------------
// blocks [0, PRE_BLKS): degree count (atomic returns per-edge rank -> erank) + graph counts.
// blocks [PRE_BLKS, PRE_BLKS+3): per-layer was/wad/weae prep (hidden under the atomic pass).
__global__ __launch_bounds__(256) void k_pre_prep(
    const int* __restrict__ dst, const int* __restrict__ batch,
    int* __restrict__ deg, float* __restrict__ gcnt, int* __restrict__ erank,
    const float* __restrict__ w1, const float* __restrict__ s1, const float* __restrict__ d1,
    const float* __restrict__ e1, const float* __restrict__ a1,
    const float* __restrict__ w2, const float* __restrict__ s2, const float* __restrict__ d2,
    const float* __restrict__ e2, const float* __restrict__ a2,
    const float* __restrict__ w3, const float* __restrict__ s3, const float* __restrict__ d3,
    const float* __restrict__ e3, const float* __restrict__ a3,
    float* __restrict__ was1, float* __restrict__ wad1, float* __restrict__ weae1,
    float* __restrict__ was2, float* __restrict__ wad2, float* __restrict__ weae2,
    float* __restrict__ was3, float* __restrict__ wad3, float* __restrict__ weae3) {
  int b = blockIdx.x;
  if (b < PRE_BLKS) {
    int e = b * 256 + threadIdx.x;
    if (e < EE) erank[e] = atomicAdd(&deg[dst[e]], 1);
    if (e < NN) atomicAdd(&gcnt[batch[e]], 1.f);
    return;
  }
  int l = b - PRE_BLKS;
  const float *W, *as_, *ad_, *We, *ae_;
  float *was, *wad, *weae;
  int K, H;
  if (l == 0) { W = w1; as_ = s1; ad_ = d1; We = e1; ae_ = a1; was = was1; wad = wad1; weae = weae1; K = FIN; H = 4; }
  else if (l == 1) { W = w2; as_ = s2; ad_ = d2; We = e2; ae_ = a2; was = was2; wad = wad2; weae = weae2; K = CC; H = 2; }
  else { W = w3; as_ = s3; ad_ = d3; We = e3; ae_ = a3; was = was3; wad = wad3; weae = weae3; K = CC; H = 4; }
  int M = H * CC;
  int tot = 2 * K * H + EDD * H;
  for (int t = threadIdx.x; t < tot; t += 256) {
    if (t < K * H) {
      int k = t / H, h = t % H;
      float s = 0.f;
      for (int c = 0; c < CC; ++c) s += W[(size_t)k * M + h * CC + c] * as_[h * CC + c];
      was[t] = s;
    } else if (t < 2 * K * H) {
      int u = t - K * H;
      int k = u / H, h = u % H;
      float s = 0.f;
      for (int c = 0; c < CC; ++c) s += W[(size_t)k * M + h * CC + c] * ad_[h * CC + c];
      wad[u] = s;
    } else {
      int u = t - 2 * K * H;
      int d = u / H, h = u % H;
      float s = 0.f;
      for (int c = 0; c < CC; ++c) s += We[(size_t)d * M + h * CC + c] * ae_[h * CC + c];
      weae[u] = s;
    }
  }
}

// hierarchical exclusive scan of deg[NN] -> row_off[NN+1]
__global__ __launch_bounds__(256) void k_scan1(const int* __restrict__ deg,
                                               int* __restrict__ row_off,
                                               int* __restrict__ bsum) {
  __shared__ int sm[256];
  int t = threadIdx.x;
  int i = blockIdx.x * 256 + t;
  int v = (i < NN) ? deg[i] : 0;
  sm[t] = v;
  __syncthreads();
  for (int off = 1; off < 256; off <<= 1) {
    int val = (t >= off) ? sm[t - off] : 0;
    __syncthreads();
    sm[t] += val;
    __syncthreads();
  }
  if (i < NN) row_off[i] = sm[t] - v;
  if (t == 255) bsum[blockIdx.x] = sm[255];
}

__global__ __launch_bounds__(256) void k_scan2(int* __restrict__ bsum, int* __restrict__ row_off) {
  __shared__ int sm[256];
  int t = threadIdx.x;
  int v = (t < SCAN_BLK) ? bsum[t] : 0;
  sm[t] = v;
  __syncthreads();
  for (int off = 1; off < 256; off <<= 1) {
    int val = (t >= off) ? sm[t - off] : 0;
    __syncthreads();
    sm[t] += val;
    __syncthreads();
  }
  if (t < SCAN_BLK) bsum[t] = sm[t] - v;
  if (t == 255) row_off[NN] = sm[255];
}

__global__ __launch_bounds__(256) void k_scan3(const int* __restrict__ bsum,
                                               int* __restrict__ row_off) {
  int i = blockIdx.x * 256 + threadIdx.x;
  if (i < NN) row_off[i] += bsum[blockIdx.x];
}

// CSR fill (NO atomics: pos = row_off[dst] + erank) + per-edge attention terms for all
// 3 layers packed into ONE 32B slot per edge -> single cacheline scatter.
__global__ __launch_bounds__(256) void k_fill(
    const int* __restrict__ src, const int* __restrict__ dst, const float* __restrict__ ea,
    const int* __restrict__ row_off, const int* __restrict__ erank,
    const float* __restrict__ weae1, const float* __restrict__ weae2,
    const float* __restrict__ weae3, unsigned int* __restrict__ edata) {
  __shared__ float w1[EDD * 4], w2[EDD * 2], w3[EDD * 4];
  int t = threadIdx.x;
  if (t < 40) w1[t] = weae1[t];
  else if (t < 60) w2[t - 40] = weae2[t - 40];
  else if (t < 100) w3[t - 60] = weae3[t - 60];
  __syncthreads();
  int e = blockIdx.x * 256 + t;
  if (e >= EE) return;
  int d = dst[e];
  int pos = row_off[d] + erank[e];
  float r[EDD];
  const float* row = ea + (size_t)e * EDD;
#pragma unroll
  for (int i2 = 0; i2 < EDD / 2; ++i2) {
    float2 v = *(const float2*)(row + 2 * i2);
    r[2 * i2] = v.x;
    r[2 * i2 + 1] = v.y;
  }
  float o1[4] = {0, 0, 0, 0}, o2[2] = {0, 0}, o3[4] = {0, 0, 0, 0};
#pragma unroll
  for (int dd = 0; dd < EDD; ++dd) {
    float rv = r[dd];
#pragma unroll
    for (int h = 0; h < 4; ++h) o1[h] += rv * w1[dd * 4 + h];
#pragma unroll
    for (int h = 0; h < 2; ++h) o2[h] += rv * w2[dd * 2 + h];
#pragma unroll
    for (int h = 0; h < 4; ++h) o3[h] += rv * w3[dd * 4 + h];
  }
  uint4 lo;
  lo.x = (unsigned int)src[e];
  lo.y = pack2(o1[0], o1[1]);
  lo.z = pack2(o1[2], o1[3]);
  lo.w = pack2(o2[0], o2[1]);
  uint2 hi;
  hi.x = pack2(o3[0], o3[1]);
  hi.y = pack2(o3[2], o3[3]);
  *(uint4*)(edata + (size_t)pos * 8) = lo;
  *(uint2*)(edata + (size_t)pos * 8 + 4) = hi;
}

// xw(fp16) = [BN(in)] @ W, plus asrc/adst epilogue.
// BN scale/shift computed per block from psum partials (fused bn_final).
template <int K, int M, int H, bool BN>
__global__ __launch_bounds__(256) void k_gemm(const float* __restrict__ in, const float* __restrict__ W,
                       const float* __restrict__ was, const float* __restrict__ wad,
                       const float* __restrict__ psum, const float* __restrict__ psum2,
                       const float* __restrict__ gamma, const float* __restrict__ beta,
                       h4* __restrict__ xw, float* __restrict__ asrc, float* __restrict__ adst) {
  constexpr int BR = 32;
  constexpr int CG = M / 4;
  constexpr int RG = 256 / CG;
  constexpr int R = BR / RG;
  __shared__ float4 xs4[BR][K / 4];
  __shared__ float s_sc[CC], s_sh[CC];
  int tid = threadIdx.x;
  if (BN) {
    bn_to_lds(psum, psum2, gamma, beta, s_sc, s_sh, tid);
    __syncthreads();
  }
  int rbase = blockIdx.x * BR;
  for (int j = tid; j < BR * K / 4; j += 256) {
    int row = j / (K / 4), kq = j % (K / 4);
    int gr = rbase + row;
    float4 v = {0.f, 0.f, 0.f, 0.f};
    if (gr < NN) v = *(const float4*)(in + (size_t)gr * K + kq * 4);
    if (BN) {
      v.x = fmaxf(v.x * s_sc[kq * 4 + 0] + s_sh[kq * 4 + 0], 0.f);
      v.y = fmaxf(v.y * s_sc[kq * 4 + 1] + s_sh[kq * 4 + 1], 0.f);
      v.z = fmaxf(v.z * s_sc[kq * 4 + 2] + s_sh[kq * 4 + 2], 0.f);
      v.w = fmaxf(v.w * s_sc[kq * 4 + 3] + s_sh[kq * 4 + 3], 0.f);
    }
    xs4[row][kq] = v;
  }
  __syncthreads();
  int cg = tid % CG, rg = tid / CG;
  int col0 = cg * 4;
  float acc[R][4];
#pragma unroll
  for (int r = 0; r < R; ++r)
#pragma unroll
    for (int c = 0; c < 4; ++c) acc[r][c] = 0.f;
  for (int k0 = 0; k0 < K; k0 += 4) {
    float4 wv[4];
#pragma unroll
    for (int kk = 0; kk < 4; ++kk) wv[kk] = *(const float4*)(W + (size_t)(k0 + kk) * M + col0);
#pragma unroll
    for (int r = 0; r < R; ++r) {
      float4 xv = xs4[rg * R + r][k0 / 4];
      const float* xf = (const float*)&xv;
#pragma unroll
      for (int kk = 0; kk < 4; ++kk) {
        const float* wf = (const float*)&wv[kk];
        float xk = xf[kk];
#pragma unroll
        for (int c = 0; c < 4; ++c) acc[r][c] += xk * wf[c];
      }
    }
  }
#pragma unroll
  for (int r = 0; r < R; ++r) {
    int gr = rbase + rg * R + r;
    if (gr < NN) {
      h4 hv;
      hv.x = (_Float16)acc[r][0]; hv.y = (_Float16)acc[r][1];
      hv.z = (_Float16)acc[r][2]; hv.w = (_Float16)acc[r][3];
      xw[(size_t)gr * (M / 4) + cg] = hv;
    }
  }
  if (tid < 2 * BR * H) {
    int which = tid / (BR * H);
    int u = tid % (BR * H);
    int row = u / H, h = u % H;
    int gr = rbase + row;
    if (gr < NN) {
      const float* wv = which ? wad : was;
      const float* xr = (const float*)&xs4[row][0];
      float s = 0.f;
      for (int k = 0; k < K; ++k) s += xr[k] * wv[k * H + h];
      (which ? adst : asrc)[(size_t)gr * H + h] = s;
    }
  }
}

// fused GAT node kernel: 16-lane group per node (4 nodes/wave), h4 gathers.
// lane g owns h4 column g+16q of its node's output -> NO acc reduce.
// Per-edge src+ae in one packed 16B load (layers 1/2) or +8B (layer 3).
// Self-loop logit from running aedge sum (linearity). BN stats fused.
template <int H, int L>
__global__ __launch_bounds__(256) void k_node(const h4* __restrict__ xw,
    const float* __restrict__ asrc, const float* __restrict__ adst,
    const unsigned int* __restrict__ edata, const int* __restrict__ row_off,
    const float* __restrict__ bias,
    float* __restrict__ out, float* __restrict__ psum, float* __restrict__ psum2) {
  constexpr int SH = (H == 4) ? 6 : 5;  // log2(h4 per row)
  int lane = threadIdx.x & 63, wid = threadIdx.x >> 6;
  int grp = lane >> 4, g = lane & 15;
  int grpbase = lane & 48;
  int n = (blockIdx.x * 4 + wid) * 4 + grp;  // grid sized so n < NN always
  int beg = row_off[n], end = row_off[n + 1];
  int deg = end - beg;
  float adh[H], asn[H], dp[H], aes[H];
  float4 acc[H];
#pragma unroll
  for (int h = 0; h < H; ++h) {
    adh[h] = adst[(size_t)n * H + h];
    asn[h] = asrc[(size_t)n * H + h];
    dp[h] = 0.f; aes[h] = 0.f;
    acc[h] = make_float4(0.f, 0.f, 0.f, 0.f);
  }
  for (int cb = beg; cb < end; cb += 16) {
    int i = cb + g;
    float p[H];
    int s = 0;
    if (i < end) {
      uint4 lo = *(const uint4*)(edata + (size_t)i * 8);
      s = (int)lo.x;
      float av[H];
      if (L == 1) {
        float2 a = unpack2(lo.y), b = unpack2(lo.z);
        av[0] = a.x; av[1] = a.y; av[2] = b.x; av[3] = b.y;
      } else if (L == 2) {
        float2 a = unpack2(lo.w);
        av[0] = a.x; av[1] = a.y;
      } else {
        uint2 hi = *(const uint2*)(edata + (size_t)i * 8 + 4);
        float2 a = unpack2(hi.x), b = unpack2(hi.y);
        av[0] = a.x; av[1] = a.y; av[2] = b.x; av[3] = b.y;
      }
      if (H == 4) {
        float4 s4 = *(const float4*)(asrc + (size_t)s * 4);
        p[0] = __expf(lrelu(s4.x + adh[0] + av[0], 0.2f));
        p[1] = __expf(lrelu(s4.y + adh[1] + av[1], 0.2f));
        p[2] = __expf(lrelu(s4.z + adh[2] + av[2], 0.2f));
        p[3] = __expf(lrelu(s4.w + adh[3] + av[3], 0.2f));
      } else {
        float2 s2 = *(const float2*)(asrc + (size_t)s * 2);
        p[0] = __expf(lrelu(s2.x + adh[0] + av[0], 0.2f));
        p[1] = __expf(lrelu(s2.y + adh[1] + av[1], 0.2f));
      }
#pragma unroll
      for (int h = 0; h < H; ++h) { dp[h] += p[h]; aes[h] += av[h]; }
    } else {
#pragma unroll
      for (int h = 0; h < H; ++h) p[h] = 0.f;
    }
    int cnt = min(16, end - cb);
    for (int j = 0; j < cnt; ++j) {
      int sl = grpbase | j;
      int sj = __shfl(s, sl);
      const h4* rb = xw + ((size_t)sj << SH) + g;
#pragma unroll
      for (int q = 0; q < H; ++q) {
        float pj = __shfl(p[q], sl);
        h4 v = rb[16 * q];
        acc[q].x += pj * (float)v.x;
        acc[q].y += pj * (float)v.y;
        acc[q].z += pj * (float)v.z;
        acc[q].w += pj * (float)v.w;
      }
    }
  }
  // reduce dp/aes within the 16-lane group (serves 4 nodes per instruction)
#pragma unroll
  for (int off = 1; off < 16; off <<= 1)
#pragma unroll
    for (int h = 0; h < H; ++h) {
      dp[h] += __shfl_xor(dp[h], off);
      aes[h] += __shfl_xor(aes[h], off);
    }
  float invd = 1.f / (float)max(deg, 1);
  float psv[H];
  const h4* rbs = xw + ((size_t)n << SH) + g;
#pragma unroll
  for (int q = 0; q < H; ++q) {
    psv[q] = __expf(lrelu(asn[q] + adh[q] + aes[q] * invd, 0.2f));
    h4 v = rbs[16 * q];
    acc[q].x += psv[q] * (float)v.x;
    acc[q].y += psv[q] * (float)v.y;
    acc[q].z += psv[q] * (float)v.z;
    acc[q].w += psv[q] * (float)v.w;
  }
  float4 res = *(const float4*)(bias + 4 * g);
#pragma unroll
  for (int q = 0; q < H; ++q) {
    float iv = (1.0f / H) / (dp[q] + psv[q]);
    res.x += acc[q].x * iv;
    res.y += acc[q].y * iv;
    res.z += acc[q].z * iv;
    res.w += acc[q].w * iv;
  }
  *(float4*)(out + (size_t)n * CC + 4 * g) = res;
  // fused BN statistics: block LDS reduce -> 64-slot rotated atomics
  __shared__ float sv[16][64], sq[16][64];
  int row = wid * 4 + grp;
  *(float4*)&sv[row][4 * g] = res;
  float4 r2;
  r2.x = res.x * res.x; r2.y = res.y * res.y; r2.z = res.z * res.z; r2.w = res.w * res.w;
  *(float4*)&sq[row][4 * g] = r2;
  __syncthreads();
  int tid = threadIdx.x;
  if (tid < 128) {
    int c = tid & 63, which = tid >> 6;
    const float(*m)[64] = which ? sq : sv;
    float ssum = 0.f;
#pragma unroll
    for (int r0 = 0; r0 < 16; ++r0) ssum += m[r0][c];
    atomicAdd((which ? psum2 : psum) + ((blockIdx.x & 63) * 64 + c), ssum);
  }
}

// final layer: BN (scale/shift computed in-block) + leaky_relu + pooled atomicAdd.
// grid-stride with 1024 blocks to bound the redundant BN-final computation.
__global__ __launch_bounds__(256) void k_bn_apply_pool(const float* __restrict__ x,
                                const float* __restrict__ psum, const float* __restrict__ psum2,
                                const float* __restrict__ gamma, const float* __restrict__ beta,
                                const int* __restrict__ batch, float* __restrict__ pooled) {
  __shared__ float s_sc[CC], s_sh[CC];
  int tid = threadIdx.x;
  bn_to_lds(psum, psum2, gamma, beta, s_sc, s_sh, tid);
  __syncthreads();
  for (int i = blockIdx.x * 256 + tid; i < NN * CC; i += gridDim.x * 256) {
    int nidx = i >> 6, c = i & 63;
    float v = x[i] * s_sc[c] + s_sh[c];
    v = lrelu(v, 0.01f);
    atomicAdd(&pooled[batch[nidx] * CC + c], v);
  }
}

__global__ __launch_bounds__(64) void k_head(const float* __restrict__ pooled,
                       const float* __restrict__ gcnt,
                       const float* __restrict__ fw1, const float* __restrict__ fb1,
                       const float* __restrict__ fw2, const float* __restrict__ fb2,
                       float* __restrict__ out) {
  int g = blockIdx.x;
  int j = threadIdx.x;
  float inv = 1.f / fmaxf(gcnt[g], 1.f);
  float h1 = fb1[j];
  for (int k = 0; k < CC; ++k) h1 += (pooled[g * CC + k] * inv) * fw1[k * CC + j];
  h1 = fmaxf(h1, 0.f);
  float o = h1 * fw2[j];
#pragma unroll
  for (int off = 32; off > 0; off >>= 1) o += __shfl_xor(o, off);
  if (j == 0) out[g] = o + fb2[0];
}

// ---------------- launch ----------------
extern "C" void kernel_launch(void* const* d_in, const int* in_sizes, int n_in,
                              void* d_out, int out_size, void* d_ws, size_t ws_size,
                              hipStream_t stream) {
  const float* x = (const float*)d_in[0];
  const int* eidx = (const int*)d_in[1];
  const float* ea = (const float*)d_in[2];
  const int* batch = (const int*)d_in[3];
  const float* w[3] = {(const float*)d_in[4], (const float*)d_in[12], (const float*)d_in[20]};
  const float* as_[3] = {(const float*)d_in[5], (const float*)d_in[13], (const float*)d_in[21]};
  const float* ad_[3] = {(const float*)d_in[6], (const float*)d_in[14], (const float*)d_in[22]};
  const float* we_[3] = {(const float*)d_in[7], (const float*)d_in[15], (const float*)d_in[23]};
  const float* ae_[3] = {(const float*)d_in[8], (const float*)d_in[16], (const float*)d_in[24]};
  const float* b_[3] = {(const float*)d_in[9], (const float*)d_in[17], (const float*)d_in[25]};
  const float* g_[3] = {(const float*)d_in[10], (const float*)d_in[18], (const float*)d_in[26]};
  const float* be_[3] = {(const float*)d_in[11], (const float*)d_in[19], (const float*)d_in[27]};
  const float* fw1 = (const float*)d_in[28];
  const float* fb1 = (const float*)d_in[29];
  const float* fw2 = (const float*)d_in[30];
  const float* fb2 = (const float*)d_in[31];
  const int* srcp = eidx;
  const int* dstp = eidx + EE;

  char* base = (char*)d_ws;
  size_t off = 0;
  auto alloc = [&](size_t bytes) {
    void* p = base + off;
    off = (off + bytes + 255) & ~(size_t)255;
    return p;
  };
  // ---- zero-init region (one memset) ----
  int* deg_i = (int*)alloc((size_t)NN * 4);
  float* pooled = (float*)alloc((size_t)GG * CC * 4);
  float* gcnt = (float*)alloc((size_t)GG * 4);
  float* psA1 = (float*)alloc((size_t)64 * 64 * 4);
  float* psB1 = (float*)alloc((size_t)64 * 64 * 4);
  float* psA2 = (float*)alloc((size_t)64 * 64 * 4);
  float* psB2 = (float*)alloc((size_t)64 * 64 * 4);
  float* psA3 = (float*)alloc((size_t)64 * 64 * 4);
  float* psB3 = (float*)alloc((size_t)64 * 64 * 4);
  size_t zero_span = off;
  // ---- rest ----
  int* row_off = (int*)alloc((size_t)(NN + 1) * 4);
  int* bsum = (int*)alloc((size_t)SCAN_BLK * 4);
  int* erank = (int*)alloc((size_t)EE * 4);
  unsigned int* edata = (unsigned int*)alloc((size_t)EE * 32);
  float* asrc = (float*)alloc((size_t)NN * 4 * 4);
  float* adst = (float*)alloc((size_t)NN * 4 * 4);
  h4* xw16 = (h4*)alloc((size_t)NN * 256 * 2);
  float* hA = (float*)alloc((size_t)NN * CC * 4);
  float* hB = (float*)alloc((size_t)NN * CC * 4);
  float* was1 = (float*)alloc((size_t)FIN * 4 * 4);
  float* wad1 = (float*)alloc((size_t)FIN * 4 * 4);
  float* weae1 = (float*)alloc(EDD * 4 * 4);
  float* was2 = (float*)alloc((size_t)CC * 2 * 4);
  float* wad2 = (float*)alloc((size_t)CC * 2 * 4);
  float* weae2 = (float*)alloc(EDD * 2 * 4);
  float* was3 = (float*)alloc((size_t)CC * 4 * 4);
  float* wad3 = (float*)alloc((size_t)CC * 4 * 4);
  float* weae3 = (float*)alloc(EDD * 4 * 4);
  (void)ws_size; (void)in_sizes; (void)n_in; (void)out_size;

  hipMemsetAsync(base, 0, zero_span, stream);

  k_pre_prep<<<PRE_BLKS + 3, 256, 0, stream>>>(
      dstp, batch, deg_i, gcnt, erank,
      w[0], as_[0], ad_[0], we_[0], ae_[0],
      w[1], as_[1], ad_[1], we_[1], ae_[1],
      w[2], as_[2], ad_[2], we_[2], ae_[2],
      was1, wad1, weae1, was2, wad2, weae2, was3, wad3, weae3);
  k_scan1<<<SCAN_BLK, 256, 0, stream>>>(deg_i, row_off, bsum);
  k_scan2<<<1, 256, 0, stream>>>(bsum, row_off);
  k_scan3<<<SCAN_BLK, 256, 0, stream>>>(bsum, row_off);
  k_fill<<<(EE + 255) / 256, 256, 0, stream>>>(srcp, dstp, ea, row_off, erank, weae1, weae2,
                                               weae3, edata);

  // layer 1 (H=4)
  k_gemm<FIN, 256, 4, false><<<(NN + 31) / 32, 256, 0, stream>>>(
      x, w[0], was1, wad1, nullptr, nullptr, nullptr, nullptr, xw16, asrc, adst);
  k_node<4, 1><<<NN / 16, 256, 0, stream>>>(xw16, asrc, adst, edata, row_off, b_[0], hA,
                                            psA1, psB1);

  // layer 2 (H=2), BN of layer 1 fused into GEMM staging (bn_final computed per block)
  k_gemm<CC, 128, 2, true><<<(NN + 31) / 32, 256, 0, stream>>>(
      hA, w[1], was2, wad2, psA1, psB1, g_[0], be_[0], xw16, asrc, adst);
  k_node<2, 2><<<NN / 16, 256, 0, stream>>>(xw16, asrc, adst, edata, row_off, b_[1], hB,
                                            psA2, psB2);

  // layer 3 (H=4)
  k_gemm<CC, 256, 4, true><<<(NN + 31) / 32, 256, 0, stream>>>(
      hB, w[2], was3, wad3, psA2, psB2, g_[1], be_[1], xw16, asrc, adst);
  k_node<4, 3><<<NN / 16, 256, 0, stream>>>(xw16, asrc, adst, edata, row_off, b_[2], hA,
                                            psA3, psB3);

  // final BN (in-block) + leaky_relu + pool
  k_bn_apply_pool<<<1024, 256, 0, stream>>>(hA, psA3, psB3, g_[2], be_[2], batch, pooled);

  k_head<<<GG, 64, 0, stream>>>(pooled, gcnt, fw1, fb1, fw2, fb2, (float*)d_out);
}

// Round 17
// 369.948 us; speedup vs baseline: 1.8620x; 1.0999x over previous
//
#include <hip/hip_runtime.h>
#include <cstdint>
#include <cstddef>

#define NN 50000
#define EE 800000
#define FIN 32
#define EDD 10
#define GG 512
#define CC 64
#define SCAN_BLK 196        // ceil(NN/256)
#define PREG_BLKS ((EE + 1023) / 1024)  // 782: 4 edges/thread
static constexpr float EPSV = 1e-5f;

typedef _Float16 h4 __attribute__((ext_vector_type(4)));
typedef _Float16 h2v __attribute__((ext_vector_type(2)));

union U32H2 { unsigned int u; h2v h; };

__device__ __forceinline__ unsigned int pack2(float a, float b) {
  U32H2 x;
  x.h.x = (_Float16)a;
  x.h.y = (_Float16)b;
  return x.u;
}
__device__ __forceinline__ float2 unpack2(unsigned int u) {
  U32H2 x;
  x.u = u;
  return make_float2((float)x.h.x, (float)x.h.y);
}

__device__ __forceinline__ float lrelu(float x, float s) { return x > 0.f ? x : s * x; }

// compute BN scale/shift into LDS from 64-slot partial sums (redundant per block; L2-hit)
__device__ __forceinline__ void bn_to_lds(const float* __restrict__ psum,
                                          const float* __restrict__ psum2,
                                          const float* __restrict__ gamma,
                                          const float* __restrict__ beta,
                                          float* s_sc, float* s_sh, int tid) {
  if (tid < CC) {
    float s = 0.f, s2 = 0.f;
#pragma unroll 8
    for (int b = 0; b < 64; ++b) {
      s += psum[b * 64 + tid];
      s2 += psum2[b * 64 + tid];
    }
    float mu = s / (float)NN;
    float var = s2 / (float)NN - mu * mu;
    float sc = gamma[tid] * rsqrtf(var + EPSV);
    s_sc[tid] = sc;
    s_sh[tid] = beta[tid] - mu * sc;
  }
}

// ---------------- preprocessing ----------------
// blocks [0, PREG_BLKS): degree count, 4 edges/thread (erank = atomic return), plus
//   wave-segmented gcnt aggregation over the SAME 4 chunks (batch sorted -> ~1 atomic/run).
// blocks [PREG_BLKS, +3): per-layer was/wad/weae prep.
__global__ __launch_bounds__(256) void k_pre_prep(
    const int* __restrict__ dst, const int* __restrict__ batch,
    int* __restrict__ deg, float* __restrict__ gcnt, int* __restrict__ erank,
    const float* __restrict__ w1, const float* __restrict__ s1, const float* __restrict__ d1,
    const float* __restrict__ e1, const float* __restrict__ a1,
    const float* __restrict__ w2, const float* __restrict__ s2, const float* __restrict__ d2,
    const float* __restrict__ e2, const float* __restrict__ a2,
    const float* __restrict__ w3, const float* __restrict__ s3, const float* __restrict__ d3,
    const float* __restrict__ e3, const float* __restrict__ a3,
    float* __restrict__ was1, float* __restrict__ wad1, float* __restrict__ weae1,
    float* __restrict__ was2, float* __restrict__ wad2, float* __restrict__ weae2,
    float* __restrict__ was3, float* __restrict__ wad3, float* __restrict__ weae3) {
  int b = blockIdx.x;
  int t = threadIdx.x;
  if (b < PREG_BLKS) {
    int e0 = b * 1024 + t;
    // 4 independent atomics in flight per thread (latency hiding)
    int dd[4];
#pragma unroll
    for (int k = 0; k < 4; ++k) {
      int e = e0 + k * 256;
      dd[k] = (e < EE) ? dst[e] : -1;
    }
#pragma unroll
    for (int k = 0; k < 4; ++k) {
      int e = e0 + k * 256;
      if (dd[k] >= 0) erank[e] = atomicAdd(&deg[dd[k]], 1);
    }
    // gcnt over all 4 chunks this block owns; batch sorted -> run aggregation per wave
    int lane = t & 63;
#pragma unroll
    for (int k = 0; k < 4; ++k) {
      int idx = e0 + k * 256;
      int g = (idx < NN) ? batch[idx] : -1;
      int prev = __shfl_up(g, 1);
      bool lead = (g >= 0) && (lane == 0 || g != prev);
      unsigned long long m = __ballot(lead);
      if (lead) {
        unsigned long long rest = (lane < 63) ? (m >> (lane + 1)) : 0ULL;
        int run = rest ? __ffsll((long long)rest) : (64 - lane);
        run = min(run, NN - idx);
        atomicAdd(&gcnt[g], (float)run);
      }
    }
    return;
  }
  int l = b - PREG_BLKS;
  const float *W, *as_, *ad_, *We, *ae_;
  float *was, *wad, *weae;
  int K, H;
  if (l == 0) { W = w1; as_ = s1; ad_ = d1; We = e1; ae_ = a1; was = was1; wad = wad1; weae = weae1; K = FIN; H = 4; }
  else if (l == 1) { W = w2; as_ = s2; ad_ = d2; We = e2; ae_ = a2; was = was2; wad = wad2; weae = weae2; K = CC; H = 2; }
  else { W = w3; as_ = s3; ad_ = d3; We = e3; ae_ = a3; was = was3; wad = wad3; weae = weae3; K = CC; H = 4; }
  int M = H * CC;
  int tot = 2 * K * H + EDD * H;
  for (int tt = t; tt < tot; tt += 256) {
    if (tt < K * H) {
      int k = tt / H, h = tt % H;
      float s = 0.f;
      for (int c = 0; c < CC; ++c) s += W[(size_t)k * M + h * CC + c] * as_[h * CC + c];
      was[tt] = s;
    } else if (tt < 2 * K * H) {
      int u = tt - K * H;
      int k = u / H, h = u % H;
      float s = 0.f;
      for (int c = 0; c < CC; ++c) s += W[(size_t)k * M + h * CC + c] * ad_[h * CC + c];
      wad[u] = s;
    } else {
      int u = tt - 2 * K * H;
      int d = u / H, h = u % H;
      float s = 0.f;
      for (int c = 0; c < CC; ++c) s += We[(size_t)d * M + h * CC + c] * ae_[h * CC + c];
      weae[u] = s;
    }
  }
}

// hierarchical exclusive scan of deg[NN] -> row_off[NN+1]
__global__ __launch_bounds__(256) void k_scan1(const int* __restrict__ deg,
                                               int* __restrict__ row_off,
                                               int* __restrict__ bsum) {
  __shared__ int sm[256];
  int t = threadIdx.x;
  int i = blockIdx.x * 256 + t;
  int v = (i < NN) ? deg[i] : 0;
  sm[t] = v;
  __syncthreads();
  for (int off = 1; off < 256; off <<= 1) {
    int val = (t >= off) ? sm[t - off] : 0;
    __syncthreads();
    sm[t] += val;
    __syncthreads();
  }
  if (i < NN) row_off[i] = sm[t] - v;
  if (t == 255) bsum[blockIdx.x] = sm[255];
}

__global__ __launch_bounds__(256) void k_scan2(int* __restrict__ bsum, int* __restrict__ row_off) {
  __shared__ int sm[256];
  int t = threadIdx.x;
  int v = (t < SCAN_BLK) ? bsum[t] : 0;
  sm[t] = v;
  __syncthreads();
  for (int off = 1; off < 256; off <<= 1) {
    int val = (t >= off) ? sm[t - off] : 0;
    __syncthreads();
    sm[t] += val;
    __syncthreads();
  }
  if (t < SCAN_BLK) bsum[t] = sm[t] - v;
  if (t == 255) row_off[NN] = sm[255];
}

__global__ __launch_bounds__(256) void k_scan3(const int* __restrict__ bsum,
                                               int* __restrict__ row_off) {
  int i = blockIdx.x * 256 + threadIdx.x;
  if (i < NN) row_off[i] += bsum[blockIdx.x];
}

// CSR fill (NO atomics: pos = row_off[dst] + erank) + per-edge attention terms for all
// 3 layers packed into ONE 32B slot per edge -> single cacheline scatter.
__global__ __launch_bounds__(256) void k_fill(
    const int* __restrict__ src, const int* __restrict__ dst, const float* __restrict__ ea,
    const int* __restrict__ row_off, const int* __restrict__ erank,
    const float* __restrict__ weae1, const float* __restrict__ weae2,
    const float* __restrict__ weae3, unsigned int* __restrict__ edata) {
  __shared__ float w1[EDD * 4], w2[EDD * 2], w3[EDD * 4];
  int t = threadIdx.x;
  if (t < 40) w1[t] = weae1[t];
  else if (t < 60) w2[t - 40] = weae2[t - 40];
  else if (t < 100) w3[t - 60] = weae3[t - 60];
  __syncthreads();
  int e = blockIdx.x * 256 + t;
  if (e >= EE) return;
  int d = dst[e];
  int pos = row_off[d] + erank[e];
  float r[EDD];
  const float* row = ea + (size_t)e * EDD;
#pragma unroll
  for (int i2 = 0; i2 < EDD / 2; ++i2) {
    float2 v = *(const float2*)(row + 2 * i2);
    r[2 * i2] = v.x;
    r[2 * i2 + 1] = v.y;
  }
  float o1[4] = {0, 0, 0, 0}, o2[2] = {0, 0}, o3[4] = {0, 0, 0, 0};
#pragma unroll
  for (int dd = 0; dd < EDD; ++dd) {
    float rv = r[dd];
#pragma unroll
    for (int h = 0; h < 4; ++h) o1[h] += rv * w1[dd * 4 + h];
#pragma unroll
    for (int h = 0; h < 2; ++h) o2[h] += rv * w2[dd * 2 + h];
#pragma unroll
    for (int h = 0; h < 4; ++h) o3[h] += rv * w3[dd * 4 + h];
  }
  uint4 lo;
  lo.x = (unsigned int)src[e];
  lo.y = pack2(o1[0], o1[1]);
  lo.z = pack2(o1[2], o1[3]);
  lo.w = pack2(o2[0], o2[1]);
  uint2 hi;
  hi.x = pack2(o3[0], o3[1]);
  hi.y = pack2(o3[2], o3[3]);
  *(uint4*)(edata + (size_t)pos * 8) = lo;
  *(uint2*)(edata + (size_t)pos * 8 + 4) = hi;
}

// xw(fp16) = [BN(in)] @ W, plus asrc/adst epilogue.
// BN scale/shift computed per block from psum partials (fused bn_final).
template <int K, int M, int H, bool BN>
__global__ __launch_bounds__(256) void k_gemm(const float* __restrict__ in, const float* __restrict__ W,
                       const float* __restrict__ was, const float* __restrict__ wad,
                       const float* __restrict__ psum, const float* __restrict__ psum2,
                       const float* __restrict__ gamma, const float* __restrict__ beta,
                       h4* __restrict__ xw, float* __restrict__ asrc, float* __restrict__ adst) {
  constexpr int BR = 32;
  constexpr int CG = M / 4;
  constexpr int RG = 256 / CG;
  constexpr int R = BR / RG;
  __shared__ float4 xs4[BR][K / 4];
  __shared__ float s_sc[CC], s_sh[CC];
  int tid = threadIdx.x;
  if (BN) {
    bn_to_lds(psum, psum2, gamma, beta, s_sc, s_sh, tid);
    __syncthreads();
  }
  int rbase = blockIdx.x * BR;
  for (int j = tid; j < BR * K / 4; j += 256) {
    int row = j / (K / 4), kq = j % (K / 4);
    int gr = rbase + row;
    float4 v = {0.f, 0.f, 0.f, 0.f};
    if (gr < NN) v = *(const float4*)(in + (size_t)gr * K + kq * 4);
    if (BN) {
      v.x = fmaxf(v.x * s_sc[kq * 4 + 0] + s_sh[kq * 4 + 0], 0.f);
      v.y = fmaxf(v.y * s_sc[kq * 4 + 1] + s_sh[kq * 4 + 1], 0.f);
      v.z = fmaxf(v.z * s_sc[kq * 4 + 2] + s_sh[kq * 4 + 2], 0.f);
      v.w = fmaxf(v.w * s_sc[kq * 4 + 3] + s_sh[kq * 4 + 3], 0.f);
    }
    xs4[row][kq] = v;
  }
  __syncthreads();
  int cg = tid % CG, rg = tid / CG;
  int col0 = cg * 4;
  float acc[R][4];
#pragma unroll
  for (int r = 0; r < R; ++r)
#pragma unroll
    for (int c = 0; c < 4; ++c) acc[r][c] = 0.f;
  for (int k0 = 0; k0 < K; k0 += 4) {
    float4 wv[4];
#pragma unroll
    for (int kk = 0; kk < 4; ++kk) wv[kk] = *(const float4*)(W + (size_t)(k0 + kk) * M + col0);
#pragma unroll
    for (int r = 0; r < R; ++r) {
      float4 xv = xs4[rg * R + r][k0 / 4];
      const float* xf = (const float*)&xv;
#pragma unroll
      for (int kk = 0; kk < 4; ++kk) {
        const float* wf = (const float*)&wv[kk];
        float xk = xf[kk];
#pragma unroll
        for (int c = 0; c < 4; ++c) acc[r][c] += xk * wf[c];
      }
    }
  }
#pragma unroll
  for (int r = 0; r < R; ++r) {
    int gr = rbase + rg * R + r;
    if (gr < NN) {
      h4 hv;
      hv.x = (_Float16)acc[r][0]; hv.y = (_Float16)acc[r][1];
      hv.z = (_Float16)acc[r][2]; hv.w = (_Float16)acc[r][3];
      xw[(size_t)gr * (M / 4) + cg] = hv;
    }
  }
  if (tid < 2 * BR * H) {
    int which = tid / (BR * H);
    int u = tid % (BR * H);
    int row = u / H, h = u % H;
    int gr = rbase + row;
    if (gr < NN) {
      const float* wv = which ? wad : was;
      const float* xr = (const float*)&xs4[row][0];
      float s = 0.f;
      for (int k = 0; k < K; ++k) s += xr[k] * wv[k * H + h];
      (which ? adst : asrc)[(size_t)gr * H + h] = s;
    }
  }
}

// fused GAT node kernel: 16-lane group per node (4 nodes/wave), h4 gathers.
// lane g owns h4 column g+16q of its node's output -> NO acc reduce.
// Per-edge src+ae in one packed 16B load (layers 1/2) or +8B (layer 3).
// Self-loop logit from running aedge sum (linearity). BN stats fused.
template <int H, int L>
__global__ __launch_bounds__(256) void k_node(const h4* __restrict__ xw,
    const float* __restrict__ asrc, const float* __restrict__ adst,
    const unsigned int* __restrict__ edata, const int* __restrict__ row_off,
    const float* __restrict__ bias,
    float* __restrict__ out, float* __restrict__ psum, float* __restrict__ psum2) {
  constexpr int SH = (H == 4) ? 6 : 5;  // log2(h4 per row)
  int lane = threadIdx.x & 63, wid = threadIdx.x >> 6;
  int grp = lane >> 4, g = lane & 15;
  int grpbase = lane & 48;
  int n = (blockIdx.x * 4 + wid) * 4 + grp;  // grid sized so n < NN always
  int beg = row_off[n], end = row_off[n + 1];
  int deg = end - beg;
  float adh[H], asn[H], dp[H], aes[H];
  float4 acc[H];
#pragma unroll
  for (int h = 0; h < H; ++h) {
    adh[h] = adst[(size_t)n * H + h];
    asn[h] = asrc[(size_t)n * H + h];
    dp[h] = 0.f; aes[h] = 0.f;
    acc[h] = make_float4(0.f, 0.f, 0.f, 0.f);
  }
  for (int cb = beg; cb < end; cb += 16) {
    int i = cb + g;
    float p[H];
    int s = 0;
    if (i < end) {
      uint4 lo = *(const uint4*)(edata + (size_t)i * 8);
      s = (int)lo.x;
      float av[H];
      if (L == 1) {
        float2 a = unpack2(lo.y), b = unpack2(lo.z);
        av[0] = a.x; av[1] = a.y; av[2] = b.x; av[3] = b.y;
      } else if (L == 2) {
        float2 a = unpack2(lo.w);
        av[0] = a.x; av[1] = a.y;
      } else {
        uint2 hi = *(const uint2*)(edata + (size_t)i * 8 + 4);
        float2 a = unpack2(hi.x), b = unpack2(hi.y);
        av[0] = a.x; av[1] = a.y; av[2] = b.x; av[3] = b.y;
      }
      if (H == 4) {
        float4 s4 = *(const float4*)(asrc + (size_t)s * 4);
        p[0] = __expf(lrelu(s4.x + adh[0] + av[0], 0.2f));
        p[1] = __expf(lrelu(s4.y + adh[1] + av[1], 0.2f));
        p[2] = __expf(lrelu(s4.z + adh[2] + av[2], 0.2f));
        p[3] = __expf(lrelu(s4.w + adh[3] + av[3], 0.2f));
      } else {
        float2 s2 = *(const float2*)(asrc + (size_t)s * 2);
        p[0] = __expf(lrelu(s2.x + adh[0] + av[0], 0.2f));
        p[1] = __expf(lrelu(s2.y + adh[1] + av[1], 0.2f));
      }
#pragma unroll
      for (int h = 0; h < H; ++h) { dp[h] += p[h]; aes[h] += av[h]; }
    } else {
#pragma unroll
      for (int h = 0; h < H; ++h) p[h] = 0.f;
    }
    int cnt = min(16, end - cb);
    for (int j = 0; j < cnt; ++j) {
      int sl = grpbase | j;
      int sj = __shfl(s, sl);
      const h4* rb = xw + ((size_t)sj << SH) + g;
#pragma unroll
      for (int q = 0; q < H; ++q) {
        float pj = __shfl(p[q], sl);
        h4 v = rb[16 * q];
        acc[q].x += pj * (float)v.x;
        acc[q].y += pj * (float)v.y;
        acc[q].z += pj * (float)v.z;
        acc[q].w += pj * (float)v.w;
      }
    }
  }
  // reduce dp/aes within the 16-lane group (serves 4 nodes per instruction)
#pragma unroll
  for (int off = 1; off < 16; off <<= 1)
#pragma unroll
    for (int h = 0; h < H; ++h) {
      dp[h] += __shfl_xor(dp[h], off);
      aes[h] += __shfl_xor(aes[h], off);
    }
  float invd = 1.f / (float)max(deg, 1);
  float psv[H];
  const h4* rbs = xw + ((size_t)n << SH) + g;
#pragma unroll
  for (int q = 0; q < H; ++q) {
    psv[q] = __expf(lrelu(asn[q] + adh[q] + aes[q] * invd, 0.2f));
    h4 v = rbs[16 * q];
    acc[q].x += psv[q] * (float)v.x;
    acc[q].y += psv[q] * (float)v.y;
    acc[q].z += psv[q] * (float)v.z;
    acc[q].w += psv[q] * (float)v.w;
  }
  float4 res = *(const float4*)(bias + 4 * g);
#pragma unroll
  for (int q = 0; q < H; ++q) {
    float iv = (1.0f / H) / (dp[q] + psv[q]);
    res.x += acc[q].x * iv;
    res.y += acc[q].y * iv;
    res.z += acc[q].z * iv;
    res.w += acc[q].w * iv;
  }
  *(float4*)(out + (size_t)n * CC + 4 * g) = res;
  // fused BN statistics: block LDS reduce -> 64-slot rotated atomics
  __shared__ float sv[16][64], sq[16][64];
  int row = wid * 4 + grp;
  *(float4*)&sv[row][4 * g] = res;
  float4 r2;
  r2.x = res.x * res.x; r2.y = res.y * res.y; r2.z = res.z * res.z; r2.w = res.w * res.w;
  *(float4*)&sq[row][4 * g] = r2;
  __syncthreads();
  int tid = threadIdx.x;
  if (tid < 128) {
    int c = tid & 63, which = tid >> 6;
    const float(*m)[64] = which ? sq : sv;
    float ssum = 0.f;
#pragma unroll
    for (int r0 = 0; r0 < 16; ++r0) ssum += m[r0][c];
    atomicAdd((which ? psum2 : psum) + ((blockIdx.x & 63) * 64 + c), ssum);
  }
}

// final layer: BN (scale/shift computed in-block) + leaky_relu + pooled atomicAdd.
__global__ __launch_bounds__(256) void k_bn_apply_pool(const float* __restrict__ x,
                                const float* __restrict__ psum, const float* __restrict__ psum2,
                                const float* __restrict__ gamma, const float* __restrict__ beta,
                                const int* __restrict__ batch, float* __restrict__ pooled) {
  __shared__ float s_sc[CC], s_sh[CC];
  int tid = threadIdx.x;
  bn_to_lds(psum, psum2, gamma, beta, s_sc, s_sh, tid);
  __syncthreads();
  for (int i = blockIdx.x * 256 + tid; i < NN * CC; i += gridDim.x * 256) {
    int nidx = i >> 6, c = i & 63;
    float v = x[i] * s_sc[c] + s_sh[c];
    v = lrelu(v, 0.01f);
    atomicAdd(&pooled[batch[nidx] * CC + c], v);
  }
}

__global__ __launch_bounds__(64) void k_head(const float* __restrict__ pooled,
                       const float* __restrict__ gcnt,
                       const float* __restrict__ fw1, const float* __restrict__ fb1,
                       const float* __restrict__ fw2, const float* __restrict__ fb2,
                       float* __restrict__ out) {
  int g = blockIdx.x;
  int j = threadIdx.x;
  float inv = 1.f / fmaxf(gcnt[g], 1.f);
  float h1 = fb1[j];
  for (int k = 0; k < CC; ++k) h1 += (pooled[g * CC + k] * inv) * fw1[k * CC + j];
  h1 = fmaxf(h1, 0.f);
  float o = h1 * fw2[j];
#pragma unroll
  for (int off = 32; off > 0; off >>= 1) o += __shfl_xor(o, off);
  if (j == 0) out[g] = o + fb2[0];
}

// ---------------- launch ----------------
extern "C" void kernel_launch(void* const* d_in, const int* in_sizes, int n_in,
                              void* d_out, int out_size, void* d_ws, size_t ws_size,
                              hipStream_t stream) {
  const float* x = (const float*)d_in[0];
  const int* eidx = (const int*)d_in[1];
  const float* ea = (const float*)d_in[2];
  const int* batch = (const int*)d_in[3];
  const float* w[3] = {(const float*)d_in[4], (const float*)d_in[12], (const float*)d_in[20]};
  const float* as_[3] = {(const float*)d_in[5], (const float*)d_in[13], (const float*)d_in[21]};
  const float* ad_[3] = {(const float*)d_in[6], (const float*)d_in[14], (const float*)d_in[22]};
  const float* we_[3] = {(const float*)d_in[7], (const float*)d_in[15], (const float*)d_in[23]};
  const float* ae_[3] = {(const float*)d_in[8], (const float*)d_in[16], (const float*)d_in[24]};
  const float* b_[3] = {(const float*)d_in[9], (const float*)d_in[17], (const float*)d_in[25]};
  const float* g_[3] = {(const float*)d_in[10], (const float*)d_in[18], (const float*)d_in[26]};
  const float* be_[3] = {(const float*)d_in[11], (const float*)d_in[19], (const float*)d_in[27]};
  const float* fw1 = (const float*)d_in[28];
  const float* fb1 = (const float*)d_in[29];
  const float* fw2 = (const float*)d_in[30];
  const float* fb2 = (const float*)d_in[31];
  const int* srcp = eidx;
  const int* dstp = eidx + EE;

  char* base = (char*)d_ws;
  size_t off = 0;
  auto alloc = [&](size_t bytes) {
    void* p = base + off;
    off = (off + bytes + 255) & ~(size_t)255;
    return p;
  };
  // ---- zero-init region (one memset) ----
  int* deg_i = (int*)alloc((size_t)NN * 4);
  float* pooled = (float*)alloc((size_t)GG * CC * 4);
  float* gcnt = (float*)alloc((size_t)GG * 4);
  float* psA1 = (float*)alloc((size_t)64 * 64 * 4);
  float* psB1 = (float*)alloc((size_t)64 * 64 * 4);
  float* psA2 = (float*)alloc((size_t)64 * 64 * 4);
  float* psB2 = (float*)alloc((size_t)64 * 64 * 4);
  float* psA3 = (float*)alloc((size_t)64 * 64 * 4);
  float* psB3 = (float*)alloc((size_t)64 * 64 * 4);
  size_t zero_span = off;
  // ---- rest ----
  int* row_off = (int*)alloc((size_t)(NN + 1) * 4);
  int* bsum = (int*)alloc((size_t)SCAN_BLK * 4);
  int* erank = (int*)alloc((size_t)EE * 4);
  unsigned int* edata = (unsigned int*)alloc((size_t)EE * 32);
  float* asrc = (float*)alloc((size_t)NN * 4 * 4);
  float* adst = (float*)alloc((size_t)NN * 4 * 4);
  h4* xw16 = (h4*)alloc((size_t)NN * 256 * 2);
  float* hA = (float*)alloc((size_t)NN * CC * 4);
  float* hB = (float*)alloc((size_t)NN * CC * 4);
  float* was1 = (float*)alloc((size_t)FIN * 4 * 4);
  float* wad1 = (float*)alloc((size_t)FIN * 4 * 4);
  float* weae1 = (float*)alloc(EDD * 4 * 4);
  float* was2 = (float*)alloc((size_t)CC * 2 * 4);
  float* wad2 = (float*)alloc((size_t)CC * 2 * 4);
  float* weae2 = (float*)alloc(EDD * 2 * 4);
  float* was3 = (float*)alloc((size_t)CC * 4 * 4);
  float* wad3 = (float*)alloc((size_t)CC * 4 * 4);
  float* weae3 = (float*)alloc(EDD * 4 * 4);
  (void)ws_size; (void)in_sizes; (void)n_in; (void)out_size;

  hipMemsetAsync(base, 0, zero_span, stream);

  k_pre_prep<<<PREG_BLKS + 3, 256, 0, stream>>>(
      dstp, batch, deg_i, gcnt, erank,
      w[0], as_[0], ad_[0], we_[0], ae_[0],
      w[1], as_[1], ad_[1], we_[1], ae_[1],
      w[2], as_[2], ad_[2], we_[2], ae_[2],
      was1, wad1, weae1, was2, wad2, weae2, was3, wad3, weae3);
  k_scan1<<<SCAN_BLK, 256, 0, stream>>>(deg_i, row_off, bsum);
  k_scan2<<<1, 256, 0, stream>>>(bsum, row_off);
  k_scan3<<<SCAN_BLK, 256, 0, stream>>>(bsum, row_off);
  k_fill<<<(EE + 255) / 256, 256, 0, stream>>>(srcp, dstp, ea, row_off, erank, weae1, weae2,
                                               weae3, edata);

  // layer 1 (H=4)
  k_gemm<FIN, 256, 4, false><<<(NN + 31) / 32, 256, 0, stream>>>(
      x, w[0], was1, wad1, nullptr, nullptr, nullptr, nullptr, xw16, asrc, adst);
  k_node<4, 1><<<NN / 16, 256, 0, stream>>>(xw16, asrc, adst, edata, row_off, b_[0], hA,
                                            psA1, psB1);

  // layer 2 (H=2), BN of layer 1 fused into GEMM staging (bn_final computed per block)
  k_gemm<CC, 128, 2, true><<<(NN + 31) / 32, 256, 0, stream>>>(
      hA, w[1], was2, wad2, psA1, psB1, g_[0], be_[0], xw16, asrc, adst);
  k_node<2, 2><<<NN / 16, 256, 0, stream>>>(xw16, asrc, adst, edata, row_off, b_[1], hB,
                                            psA2, psB2);

  // layer 3 (H=4)
  k_gemm<CC, 256, 4, true><<<(NN + 31) / 32, 256, 0, stream>>>(
      hB, w[2], was3, wad3, psA2, psB2, g_[1], be_[1], xw16, asrc, adst);
  k_node<4, 3><<<NN / 16, 256, 0, stream>>>(xw16, asrc, adst, edata, row_off, b_[2], hA,
                                            psA3, psB3);

  // final BN (in-block) + leaky_relu + pool
  k_bn_apply_pool<<<1024, 256, 0, stream>>>(hA, psA3, psB3, g_[2], be_[2], batch, pooled);

  k_head<<<GG, 64, 0, stream>>>(pooled, gcnt, fw1, fb1, fw2, fb2, (float*)d_out);
}